// Round 1
// baseline (1751.309 us; speedup 1.0000x reference)
//
#include <hip/hip_runtime.h>
#include <math.h>

#define N_NODES 50000
#define N_EDGES 800000
#define T_G 4
#define IN_F 128
#define HID_F 64
#define OUT_F 3
#define H_M 8

__device__ __forceinline__ float lrelu(float v) { return v > 0.f ? v : 0.2f * v; }

// ---- weight-vector precompute: w[0:4]=fc2_w.mean(0), w[4:8]=fc3_w.mean(0)
__global__ void k_wvec(const float* __restrict__ fc2, const float* __restrict__ fc3,
                       float* __restrict__ w) {
    int t = threadIdx.x;
    if (t < T_G) {
        float a = 0.f, b = 0.f;
        for (int i = 0; i < T_G; i++) { a += fc2[i * T_G + t]; b += fc3[i * T_G + t]; }
        w[t] = 0.25f * a;
        w[T_G + t] = 0.25f * b;
    }
}

// ---- layer-1 GEMM: feat1[t,n,c] = sum_k x[n,k]*W1[t,k,c]; fused el/er wave-reductions
__global__ __launch_bounds__(256) void k_gemm1(
    const float* __restrict__ x, const float* __restrict__ W1,
    const float* __restrict__ al1, const float* __restrict__ ar1,
    float* __restrict__ feat1, float* __restrict__ el1, float* __restrict__ er1) {
    __shared__ float Wl[IN_F * HID_F];  // 32 KB
    __shared__ float Xl[16 * IN_F];     // 8 KB
    int t = blockIdx.y;
    int base = blockIdx.x * 16;  // 3125*16 == 50000 exactly
    for (int i = threadIdx.x; i < IN_F * HID_F; i += 256) Wl[i] = W1[t * IN_F * HID_F + i];
    for (int i = threadIdx.x; i < 16 * IN_F; i += 256) Xl[i] = x[base * IN_F + i];
    __syncthreads();
    int c = threadIdx.x & 63;
    int rq = threadIdx.x >> 6;
    float acc[4] = {0.f, 0.f, 0.f, 0.f};
    for (int k = 0; k < IN_F; k++) {
        float w = Wl[k * HID_F + c];
#pragma unroll
        for (int i = 0; i < 4; i++) acc[i] += Xl[(rq * 4 + i) * IN_F + k] * w;
    }
    float alv = al1[t * HID_F + c], arv = ar1[t * HID_F + c];
#pragma unroll
    for (int i = 0; i < 4; i++) {
        int row = base + rq * 4 + i;
        feat1[((long)t * N_NODES + row) * HID_F + c] = acc[i];
        float vl = acc[i] * alv, vr = acc[i] * arv;
#pragma unroll
        for (int off = 32; off; off >>= 1) { vl += __shfl_xor(vl, off); vr += __shfl_xor(vr, off); }
        if (c == 0) { el1[t * N_NODES + row] = vl; er1[t * N_NODES + row] = vr; }
    }
}

// ---- CSR build (by dst), shared by all 4 layers
__global__ void k_count(const int* __restrict__ edges, int* __restrict__ deg) {
    int t = blockIdx.y;
    const int* dst = edges + (t * 2 + 1) * N_EDGES;
    int i = blockIdx.x * blockDim.x + threadIdx.x;
    if (i < N_EDGES) atomicAdd(&deg[t * N_NODES + dst[i]], 1);
}

__global__ __launch_bounds__(1024) void k_scan(const int* __restrict__ deg, int* __restrict__ rowptr) {
    int t = blockIdx.x;
    __shared__ int buf[1024];
    __shared__ int carry;
    if (threadIdx.x == 0) carry = 0;
    __syncthreads();
    for (int base = 0; base < N_NODES; base += 1024) {
        int i = base + threadIdx.x;
        int v = (i < N_NODES) ? deg[t * N_NODES + i] : 0;
        buf[threadIdx.x] = v;
        __syncthreads();
        for (int off = 1; off < 1024; off <<= 1) {
            int add = (threadIdx.x >= (unsigned)off) ? buf[threadIdx.x - off] : 0;
            __syncthreads();
            buf[threadIdx.x] += add;
            __syncthreads();
        }
        if (i < N_NODES) rowptr[t * N_NODES + i] = carry + buf[threadIdx.x] - v;  // exclusive
        int tot = buf[1023];
        __syncthreads();
        if (threadIdx.x == 0) carry += tot;
        __syncthreads();
    }
}

__global__ void k_scatter(const int* __restrict__ edges, const int* __restrict__ rowptr,
                          int* __restrict__ cursor, int* __restrict__ csr_src) {
    int t = blockIdx.y;
    const int* srcp = edges + (t * 2 + 0) * N_EDGES;
    const int* dstp = edges + (t * 2 + 1) * N_EDGES;
    int i = blockIdx.x * blockDim.x + threadIdx.x;
    if (i < N_EDGES) {
        int d = dstp[i];
        int pos = rowptr[t * N_NODES + d] + atomicAdd(&cursor[t * N_NODES + d], 1);
        csr_src[t * N_EDGES + pos] = srcp[i];
    }
}

// ---- layer-1 aggregation: wave per node, lane = feature; mean over t fused
__global__ __launch_bounds__(256) void k_agg1(
    const float* __restrict__ feat1, const float* __restrict__ el1, const float* __restrict__ er1,
    const int* __restrict__ rowptr, const int* __restrict__ deg, const int* __restrict__ csr_src,
    const float* __restrict__ b1, float* __restrict__ h1) {
    int node = blockIdx.x * 4 + (threadIdx.x >> 6);
    int lane = threadIdx.x & 63;
    if (node >= N_NODES) return;
    float acc = 0.f;
    for (int t = 0; t < T_G; t++) {
        int beg = rowptr[t * N_NODES + node];
        int cnt = deg[t * N_NODES + node];
        if (cnt == 0) continue;
        float ern = er1[t * N_NODES + node];
        const int* cs = csr_src + t * N_EDGES;
        const float* el = el1 + t * N_NODES;
        const float* ft = feat1 + (long)t * N_NODES * HID_F;
        float m = -1e30f;
        for (int e = beg; e < beg + cnt; e++) m = fmaxf(m, lrelu(el[cs[e]] + ern));
        float ssum = 0.f, accT = 0.f;
        for (int e = beg; e < beg + cnt; e++) {
            int s = cs[e];
            float p = __expf(lrelu(el[s] + ern) - m);
            ssum += p;
            accT += p * ft[s * HID_F + lane];
        }
        acc += accT / ssum;
    }
    float bterm = 0.25f * (b1[lane] + b1[HID_F + lane] + b1[2 * HID_F + lane] + b1[3 * HID_F + lane]);
    h1[node * HID_F + lane] = 0.25f * acc + bterm;
}

// ---- layer-2 featurization: feat2[t,n,0:3], el2, er2 from h1 (N,64)
__global__ __launch_bounds__(256) void k_feat2(
    const float* __restrict__ h1, const float* __restrict__ W2,
    const float* __restrict__ al2, const float* __restrict__ ar2,
    float* __restrict__ feat2, float* __restrict__ el2, float* __restrict__ er2) {
    __shared__ float Wl[T_G * HID_F * OUT_F];
    __shared__ float Al[T_G * OUT_F], Ar[T_G * OUT_F];
    for (int i = threadIdx.x; i < T_G * HID_F * OUT_F; i += 256) Wl[i] = W2[i];
    if (threadIdx.x < T_G * OUT_F) { Al[threadIdx.x] = al2[threadIdx.x]; Ar[threadIdx.x] = ar2[threadIdx.x]; }
    __syncthreads();
    int n = blockIdx.x * 256 + threadIdx.x;
    if (n >= N_NODES) return;
    float h[HID_F];
    const float4* hp = (const float4*)(h1 + n * HID_F);
#pragma unroll
    for (int i = 0; i < 16; i++) {
        float4 v = hp[i];
        h[4 * i] = v.x; h[4 * i + 1] = v.y; h[4 * i + 2] = v.z; h[4 * i + 3] = v.w;
    }
    for (int t = 0; t < T_G; t++) {
        float f0 = 0.f, f1 = 0.f, f2 = 0.f;
#pragma unroll
        for (int k = 0; k < HID_F; k++) {
            float hv = h[k];
            f0 += hv * Wl[(t * HID_F + k) * 3 + 0];
            f1 += hv * Wl[(t * HID_F + k) * 3 + 1];
            f2 += hv * Wl[(t * HID_F + k) * 3 + 2];
        }
        long ob = ((long)t * N_NODES + n) * 3;
        feat2[ob] = f0; feat2[ob + 1] = f1; feat2[ob + 2] = f2;
        el2[t * N_NODES + n] = f0 * Al[t * 3] + f1 * Al[t * 3 + 1] + f2 * Al[t * 3 + 2];
        er2[t * N_NODES + n] = f0 * Ar[t * 3] + f1 * Ar[t * 3 + 1] + f2 * Ar[t * 3 + 2];
    }
}

// ---- aggregation for d=3 layers: thread per (node,t), raw (unweighted) output
__global__ __launch_bounds__(256) void k_agg3f(
    const float* __restrict__ feat, const float* __restrict__ el_, const float* __restrict__ er_,
    const int* __restrict__ rowptr, const int* __restrict__ deg, const int* __restrict__ csr_src,
    float* __restrict__ outp) {
    int n = blockIdx.x * 256 + threadIdx.x;
    int t = blockIdx.y;
    if (n >= N_NODES) return;
    int beg = rowptr[t * N_NODES + n], cnt = deg[t * N_NODES + n];
    float o0 = 0.f, o1 = 0.f, o2 = 0.f;
    if (cnt > 0) {
        float ern = er_[t * N_NODES + n];
        const int* cs = csr_src + t * N_EDGES;
        const float* el = el_ + t * N_NODES;
        const float* ft = feat + (long)t * N_NODES * 3;
        float m = -1e30f;
        for (int e = beg; e < beg + cnt; e++) m = fmaxf(m, lrelu(el[cs[e]] + ern));
        float ssum = 0.f;
        for (int e = beg; e < beg + cnt; e++) {
            int s = cs[e];
            float p = __expf(lrelu(el[s] + ern) - m);
            ssum += p;
            o0 += p * ft[s * 3];
            o1 += p * ft[s * 3 + 1];
            o2 += p * ft[s * 3 + 2];
        }
        float inv = 1.f / ssum;
        o0 *= inv; o1 *= inv; o2 *= inv;
    }
    long ob = ((long)t * N_NODES + n) * 3;
    outp[ob] = o0; outp[ob + 1] = o1; outp[ob + 2] = o2;
}

// ---- combine: h[n,d] = sum_t w[t]*(out[t,n,d] + b[t,d])
__global__ void k_comb3(const float* __restrict__ outp, const float* __restrict__ b,
                        const float* __restrict__ w, float* __restrict__ h) {
    int n = blockIdx.x * 256 + threadIdx.x;
    if (n >= N_NODES) return;
    float r0 = 0.f, r1 = 0.f, r2 = 0.f;
    for (int t = 0; t < T_G; t++) {
        float wt = w[t];
        long ob = ((long)t * N_NODES + n) * 3;
        r0 += wt * (outp[ob] + b[t * 3]);
        r1 += wt * (outp[ob + 1] + b[t * 3 + 1]);
        r2 += wt * (outp[ob + 2] + b[t * 3 + 2]);
    }
    h[n * 3] = r0; h[n * 3 + 1] = r1; h[n * 3 + 2] = r2;
}

// ---- layer-3 featurization (3->3)
__global__ void k_feat3(const float* __restrict__ h2, const float* __restrict__ W3,
                        const float* __restrict__ al3, const float* __restrict__ ar3,
                        float* __restrict__ feat3, float* __restrict__ el3, float* __restrict__ er3) {
    int n = blockIdx.x * 256 + threadIdx.x;
    if (n >= N_NODES) return;
    float h0 = h2[n * 3], h1v = h2[n * 3 + 1], h2v = h2[n * 3 + 2];
    for (int t = 0; t < T_G; t++) {
        float el = 0.f, er = 0.f;
#pragma unroll
        for (int d = 0; d < 3; d++) {
            float f = h0 * W3[(t * 3 + 0) * 3 + d] + h1v * W3[(t * 3 + 1) * 3 + d] + h2v * W3[(t * 3 + 2) * 3 + d];
            feat3[((long)t * N_NODES + n) * 3 + d] = f;
            el += f * al3[t * 3 + d];
            er += f * ar3[t * 3 + d];
        }
        el3[t * N_NODES + n] = el;
        er3[t * N_NODES + n] = er;
    }
}

// ---- layer-M featurization (3 -> 8 heads x 3)
__global__ void k_featM(const float* __restrict__ h3, const float* __restrict__ WM,
                        const float* __restrict__ alM, const float* __restrict__ arM,
                        float* __restrict__ featM, float* __restrict__ elM, float* __restrict__ erM) {
    int n = blockIdx.x * 256 + threadIdx.x;
    if (n >= N_NODES) return;
    float h0 = h3[n * 3], h1v = h3[n * 3 + 1], h2v = h3[n * 3 + 2];
    for (int t = 0; t < T_G; t++) {
#pragma unroll
        for (int hh = 0; hh < H_M; hh++) {
            float el = 0.f, er = 0.f;
#pragma unroll
            for (int d = 0; d < 3; d++) {
                int j = hh * 3 + d;
                float f = h0 * WM[(t * 3 + 0) * 24 + j] + h1v * WM[(t * 3 + 1) * 24 + j] + h2v * WM[(t * 3 + 2) * 24 + j];
                featM[((long)t * N_NODES + n) * 24 + j] = f;
                el += f * alM[(t * H_M + hh) * 3 + d];
                er += f * arM[(t * H_M + hh) * 3 + d];
            }
            elM[((long)t * N_NODES + n) * 8 + hh] = el;
            erM[((long)t * N_NODES + n) * 8 + hh] = er;
        }
    }
}

// ---- layer-M aggregation: thread per (node,t), 8 heads
__global__ __launch_bounds__(256) void k_aggM(
    const float* __restrict__ featM, const float* __restrict__ elM, const float* __restrict__ erM,
    const int* __restrict__ rowptr, const int* __restrict__ deg, const int* __restrict__ csr_src,
    float* __restrict__ outM) {
    int n = blockIdx.x * 256 + threadIdx.x;
    int t = blockIdx.y;
    if (n >= N_NODES) return;
    int beg = rowptr[t * N_NODES + n], cnt = deg[t * N_NODES + n];
    float acc[24];
#pragma unroll
    for (int j = 0; j < 24; j++) acc[j] = 0.f;
    if (cnt > 0) {
        float ern[8], mx[8], ssum[8];
#pragma unroll
        for (int hh = 0; hh < 8; hh++) {
            ern[hh] = erM[((long)t * N_NODES + n) * 8 + hh];
            mx[hh] = -1e30f;
            ssum[hh] = 0.f;
        }
        const int* cs = csr_src + t * N_EDGES;
        for (int e = beg; e < beg + cnt; e++) {
            int s = cs[e];
            const float* elp = elM + ((long)t * N_NODES + s) * 8;
#pragma unroll
            for (int hh = 0; hh < 8; hh++) mx[hh] = fmaxf(mx[hh], lrelu(elp[hh] + ern[hh]));
        }
        for (int e = beg; e < beg + cnt; e++) {
            int s = cs[e];
            const float* elp = elM + ((long)t * N_NODES + s) * 8;
            const float* fp = featM + ((long)t * N_NODES + s) * 24;
#pragma unroll
            for (int hh = 0; hh < 8; hh++) {
                float p = __expf(lrelu(elp[hh] + ern[hh]) - mx[hh]);
                ssum[hh] += p;
                acc[hh * 3] += p * fp[hh * 3];
                acc[hh * 3 + 1] += p * fp[hh * 3 + 1];
                acc[hh * 3 + 2] += p * fp[hh * 3 + 2];
            }
        }
#pragma unroll
        for (int hh = 0; hh < 8; hh++) {
            float inv = 1.f / ssum[hh];
            acc[hh * 3] *= inv; acc[hh * 3 + 1] *= inv; acc[hh * 3 + 2] *= inv;
        }
    }
    float* op = outM + ((long)t * N_NODES + n) * 24;
#pragma unroll
    for (int j = 0; j < 24; j++) op[j] = acc[j];
}

__global__ void k_combM(const float* __restrict__ outM, const float* __restrict__ bM,
                        const float* __restrict__ w3, float* __restrict__ hM) {
    int n = blockIdx.x * 256 + threadIdx.x;
    if (n >= N_NODES) return;
    float r[24];
#pragma unroll
    for (int j = 0; j < 24; j++) r[j] = 0.f;
    for (int t = 0; t < T_G; t++) {
        float wt = w3[t];
        const float* op = outM + ((long)t * N_NODES + n) * 24;
#pragma unroll
        for (int j = 0; j < 24; j++) r[j] += wt * (op[j] + bM[t * 24 + j]);
    }
#pragma unroll
    for (int j = 0; j < 24; j++) hM[n * 24 + j] = r[j];
}

// ---- delta norms per head: norms[h, n] = ||hM[n,h,:] - hM[n-1,h,:]||
__global__ void k_norms(const float* __restrict__ hM, float* __restrict__ norms) {
    int idx = blockIdx.x * 256 + threadIdx.x;
    if (idx >= N_NODES * H_M) return;
    int n = idx >> 3, hh = idx & 7;
    float s = 0.f;
#pragma unroll
    for (int d = 0; d < 3; d++) {
        float cur = hM[n * 24 + hh * 3 + d];
        float prev = (n > 0) ? hM[(n - 1) * 24 + hh * 3 + d] : 0.f;
        float dx = cur - prev;
        s += dx * dx;
    }
    norms[hh * N_NODES + n] = sqrtf(s);
}

// ---- exact median via MSB->LSB radix select (values are non-negative floats)
__global__ __launch_bounds__(256) void k_median(const float* __restrict__ norms, float* __restrict__ med) {
    int hh = blockIdx.x;
    const float* v = norms + (long)hh * N_NODES;
    __shared__ unsigned int hist[256];
    __shared__ unsigned int s_sel, s_rank;
    float res[2];
    for (int kk = 0; kk < 2; kk++) {
        unsigned int prefix = 0;
        unsigned int rank = N_NODES / 2 - 1 + kk;  // 24999, 25000
        for (int byte = 3; byte >= 0; byte--) {
            hist[threadIdx.x] = 0;
            __syncthreads();
            unsigned int shift = byte * 8;
            unsigned int maskU = (byte == 3) ? 0u : (0xFFFFFFFFu << (shift + 8));
            for (int i = threadIdx.x; i < N_NODES; i += 256) {
                unsigned int u = __float_as_uint(v[i]);
                if ((u & maskU) == prefix) atomicAdd(&hist[(u >> shift) & 255u], 1u);
            }
            __syncthreads();
            if (threadIdx.x == 0) {
                unsigned int accu = 0;
                for (int b = 0; b < 256; b++) {
                    unsigned int c = hist[b];
                    if (accu + c > rank) { s_sel = prefix | ((unsigned)b << shift); s_rank = rank - accu; break; }
                    accu += c;
                }
            }
            __syncthreads();
            prefix = s_sel;
            rank = s_rank;
            __syncthreads();
        }
        res[kk] = __uint_as_float(prefix);
    }
    if (threadIdx.x == 0) med[hh] = 0.5f * (res[0] + res[1]) + 1e-4f;
}

// ---- final: out = nan_to_num(hM/med[h]) + 0.3*noise
__global__ void k_final(const float* __restrict__ hM, const float* __restrict__ med,
                        const float* __restrict__ noise, float* __restrict__ out) {
    int idx = blockIdx.x * 256 + threadIdx.x;
    if (idx >= N_NODES * 24) return;
    int hh = (idx / 3) & 7;
    float v = hM[idx] / med[hh];
    if (isnan(v)) v = 0.f;
    else if (isinf(v)) v = v > 0.f ? 100.f : -100.f;
    out[idx] = v + 0.3f * noise[idx];
}

extern "C" void kernel_launch(void* const* d_in, const int* in_sizes, int n_in,
                              void* d_out, int out_size, void* d_ws, size_t ws_size,
                              hipStream_t stream) {
    const float* x     = (const float*)d_in[0];
    const int*   edges = (const int*)d_in[1];
    const float* noise = (const float*)d_in[2];
    const float* W1  = (const float*)d_in[3];
    const float* al1 = (const float*)d_in[4];
    const float* ar1 = (const float*)d_in[5];
    const float* b1  = (const float*)d_in[6];
    const float* W2  = (const float*)d_in[7];
    const float* al2 = (const float*)d_in[8];
    const float* ar2 = (const float*)d_in[9];
    const float* b2  = (const float*)d_in[10];
    const float* W3  = (const float*)d_in[11];
    const float* al3 = (const float*)d_in[12];
    const float* ar3 = (const float*)d_in[13];
    const float* b3  = (const float*)d_in[14];
    const float* WM  = (const float*)d_in[15];
    const float* alM = (const float*)d_in[16];
    const float* arM = (const float*)d_in[17];
    const float* bM  = (const float*)d_in[18];
    const float* fc2 = (const float*)d_in[19];
    const float* fc3 = (const float*)d_in[20];
    float* out = (float*)d_out;

    // ---- workspace layout (bump allocator, 256B aligned) ----
    char* basep = (char*)d_ws;
    size_t off = 0;
    auto alloc = [&](size_t bytes) -> void* {
        void* p = basep + off;
        off += (bytes + 255) & ~(size_t)255;
        return p;
    };
    // Region A: feat1 (T*N*64 floats = 51.2MB), later reused for layer-M buffers
    float* feat1 = (float*)alloc((size_t)T_G * N_NODES * HID_F * 4);
    float* featM = feat1;                    // T*N*24 = 4.8M floats
    float* elM   = feat1 + 4800000;          // T*N*8  = 1.6M
    float* erM   = feat1 + 6400000;          // T*N*8  = 1.6M
    float* outM  = feat1 + 8000000;          // T*N*24 = 4.8M  (ends exactly at 12.8M)
    float* el1 = (float*)alloc((size_t)T_G * N_NODES * 4);
    float* er1 = (float*)alloc((size_t)T_G * N_NODES * 4);
    float* h1  = (float*)alloc((size_t)N_NODES * HID_F * 4);
    float* feat2 = (float*)alloc((size_t)T_G * N_NODES * 3 * 4);
    float* el2 = (float*)alloc((size_t)T_G * N_NODES * 4);
    float* er2 = (float*)alloc((size_t)T_G * N_NODES * 4);
    float* out2 = (float*)alloc((size_t)T_G * N_NODES * 3 * 4);
    float* h2  = (float*)alloc((size_t)N_NODES * 3 * 4);
    float* feat3 = (float*)alloc((size_t)T_G * N_NODES * 3 * 4);
    float* el3 = (float*)alloc((size_t)T_G * N_NODES * 4);
    float* er3 = (float*)alloc((size_t)T_G * N_NODES * 4);
    float* out3 = (float*)alloc((size_t)T_G * N_NODES * 3 * 4);
    float* h3  = (float*)alloc((size_t)N_NODES * 3 * 4);
    float* hM  = (float*)alloc((size_t)N_NODES * 24 * 4);
    float* norms = (float*)alloc((size_t)H_M * N_NODES * 4);
    float* med = (float*)alloc(64);
    float* wbuf = (float*)alloc(64);
    int* deg    = (int*)alloc((size_t)T_G * N_NODES * 4);
    int* cursor = (int*)alloc((size_t)T_G * N_NODES * 4);
    int* rowptr = (int*)alloc((size_t)T_G * N_NODES * 4);
    int* csr_src = (int*)alloc((size_t)T_G * N_EDGES * 4);

    const int NB = (N_NODES + 255) / 256;  // 196

    hipMemsetAsync(deg, 0, (size_t)T_G * N_NODES * 4, stream);
    hipMemsetAsync(cursor, 0, (size_t)T_G * N_NODES * 4, stream);

    k_wvec<<<1, 64, 0, stream>>>(fc2, fc3, wbuf);

    // CSR build (reused by all layers)
    k_count<<<dim3(N_EDGES / 256, T_G), 256, 0, stream>>>(edges, deg);
    k_scan<<<T_G, 1024, 0, stream>>>(deg, rowptr);
    k_scatter<<<dim3(N_EDGES / 256, T_G), 256, 0, stream>>>(edges, rowptr, cursor, csr_src);

    // Layer 1
    k_gemm1<<<dim3(N_NODES / 16, T_G), 256, 0, stream>>>(x, W1, al1, ar1, feat1, el1, er1);
    k_agg1<<<N_NODES / 4, 256, 0, stream>>>(feat1, el1, er1, rowptr, deg, csr_src, b1, h1);

    // Layer 2
    k_feat2<<<NB, 256, 0, stream>>>(h1, W2, al2, ar2, feat2, el2, er2);
    k_agg3f<<<dim3(NB, T_G), 256, 0, stream>>>(feat2, el2, er2, rowptr, deg, csr_src, out2);
    k_comb3<<<NB, 256, 0, stream>>>(out2, b2, wbuf, h2);

    // Layer 3
    k_feat3<<<NB, 256, 0, stream>>>(h2, W3, al3, ar3, feat3, el3, er3);
    k_agg3f<<<dim3(NB, T_G), 256, 0, stream>>>(feat3, el3, er3, rowptr, deg, csr_src, out3);
    k_comb3<<<NB, 256, 0, stream>>>(out3, b3, wbuf + 4, h3);

    // Layer M (reuses feat1's region — feat1 is dead after k_agg1)
    k_featM<<<NB, 256, 0, stream>>>(h3, WM, alM, arM, featM, elM, erM);
    k_aggM<<<dim3(NB, T_G), 256, 0, stream>>>(featM, elM, erM, rowptr, deg, csr_src, outM);
    k_combM<<<NB, 256, 0, stream>>>(outM, bM, wbuf + 4, hM);

    // norm_ (telescoped): medians of delta-norms, then scale + noise
    k_norms<<<(N_NODES * H_M + 255) / 256, 256, 0, stream>>>(hM, norms);
    k_median<<<H_M, 256, 0, stream>>>(norms, med);
    k_final<<<(N_NODES * 24 + 255) / 256, 256, 0, stream>>>(hM, med, noise, out);
}

// Round 2
// 1652.448 us; speedup vs baseline: 1.0598x; 1.0598x over previous
//
#include <hip/hip_runtime.h>
#include <hip/hip_bf16.h>
#include <math.h>

#define N_NODES 50000
#define N_EDGES 800000
#define T_G 4
#define IN_F 128
#define HID_F 64
#define OUT_F 3
#define H_M 8

__device__ __forceinline__ float lrelu(float v) { return v > 0.f ? v : 0.2f * v; }

__device__ __forceinline__ float wred_max(float v) {
#pragma unroll
    for (int o = 32; o; o >>= 1) v = fmaxf(v, __shfl_xor(v, o));
    return v;
}
__device__ __forceinline__ float wred_sum(float v) {
#pragma unroll
    for (int o = 32; o; o >>= 1) v += __shfl_xor(v, o);
    return v;
}

// ---- weight/bias precompute:
// wbuf[0:4]=w2 (fc2 col-mean), [4:8]=w3 (fc3 col-mean), [8:11]=cb2, [11:14]=cb3, [16:40]=cbM
__global__ void k_wvec(const float* __restrict__ fc2, const float* __restrict__ fc3,
                       const float* __restrict__ b2, const float* __restrict__ b3,
                       const float* __restrict__ bM, float* __restrict__ w) {
    __shared__ float w2[4], w3[4];
    int i = threadIdx.x;
    if (i < 4) {
        float a = 0.f, b = 0.f;
        for (int r = 0; r < T_G; r++) { a += fc2[r * T_G + i]; b += fc3[r * T_G + i]; }
        w2[i] = 0.25f * a; w3[i] = 0.25f * b;
        w[i] = w2[i]; w[4 + i] = w3[i];
    }
    __syncthreads();
    if (i < 3) {
        float c = 0.f;
        for (int t = 0; t < T_G; t++) c += w2[t] * b2[t * 3 + i];
        w[8 + i] = c;
    }
    if (i >= 8 && i < 11) {
        int d = i - 8;
        float c = 0.f;
        for (int t = 0; t < T_G; t++) c += w3[t] * b3[t * 3 + d];
        w[11 + d] = c;
    }
    if (i >= 16 && i < 40) {
        int j = i - 16;
        float c = 0.f;
        for (int t = 0; t < T_G; t++) c += w3[t] * bM[t * 24 + j];
        w[16 + j] = c;
    }
}

__global__ void k_initrep(float* __restrict__ dst, int n, const float* __restrict__ src, int period) {
    int i = blockIdx.x * 256 + threadIdx.x;
    if (i < n) dst[i] = src[i % period];
}

// ---- layer-1 GEMM: feat1(bf16)[t,n,c], el1/er1 from f32 accs
__global__ __launch_bounds__(256) void k_gemm1(
    const float* __restrict__ x, const float* __restrict__ W1,
    const float* __restrict__ al1, const float* __restrict__ ar1,
    __hip_bfloat16* __restrict__ feat1, float* __restrict__ el1, float* __restrict__ er1) {
    __shared__ float Wl[IN_F * HID_F];  // 32 KB
    __shared__ float Xl[16 * IN_F];     // 8 KB
    int t = blockIdx.y;
    int base = blockIdx.x * 16;
    for (int i = threadIdx.x; i < IN_F * HID_F; i += 256) Wl[i] = W1[t * IN_F * HID_F + i];
    for (int i = threadIdx.x; i < 16 * IN_F; i += 256) Xl[i] = x[base * IN_F + i];
    __syncthreads();
    int c = threadIdx.x & 63;
    int rq = threadIdx.x >> 6;
    float acc[4] = {0.f, 0.f, 0.f, 0.f};
    for (int k = 0; k < IN_F; k++) {
        float w = Wl[k * HID_F + c];
#pragma unroll
        for (int i = 0; i < 4; i++) acc[i] += Xl[(rq * 4 + i) * IN_F + k] * w;
    }
    float alv = al1[t * HID_F + c], arv = ar1[t * HID_F + c];
#pragma unroll
    for (int i = 0; i < 4; i++) {
        int row = base + rq * 4 + i;
        feat1[(t * N_NODES + row) * HID_F + c] = __float2bfloat16(acc[i]);
        float vl = acc[i] * alv, vr = acc[i] * arv;
#pragma unroll
        for (int off = 32; off; off >>= 1) { vl += __shfl_xor(vl, off); vr += __shfl_xor(vr, off); }
        if (c == 0) { el1[t * N_NODES + row] = vl; er1[t * N_NODES + row] = vr; }
    }
}

// ---- CSR build (by dst)
__global__ void k_count(const int* __restrict__ edges, int* __restrict__ deg) {
    int t = blockIdx.y;
    const int* dst = edges + (t * 2 + 1) * N_EDGES;
    int i = blockIdx.x * blockDim.x + threadIdx.x;
    if (i < N_EDGES) atomicAdd(&deg[t * N_NODES + dst[i]], 1);
}

__global__ __launch_bounds__(1024) void k_scan(const int* __restrict__ deg, int* __restrict__ rowptr) {
    int t = blockIdx.x;
    __shared__ int buf[1024];
    __shared__ int carry;
    if (threadIdx.x == 0) carry = 0;
    __syncthreads();
    for (int base = 0; base < N_NODES; base += 1024) {
        int i = base + threadIdx.x;
        int v = (i < N_NODES) ? deg[t * N_NODES + i] : 0;
        buf[threadIdx.x] = v;
        __syncthreads();
        for (int off = 1; off < 1024; off <<= 1) {
            int add = (threadIdx.x >= (unsigned)off) ? buf[threadIdx.x - off] : 0;
            __syncthreads();
            buf[threadIdx.x] += add;
            __syncthreads();
        }
        if (i < N_NODES) rowptr[t * N_NODES + i] = carry + buf[threadIdx.x] - v;  // exclusive
        int tot = buf[1023];
        __syncthreads();
        if (threadIdx.x == 0) carry += tot;
        __syncthreads();
    }
}

__global__ void k_scatter(const int* __restrict__ edges, const int* __restrict__ rowptr,
                          int* __restrict__ cursor, int* __restrict__ csr_src) {
    int t = blockIdx.y;
    const int* srcp = edges + (t * 2 + 0) * N_EDGES;
    const int* dstp = edges + (t * 2 + 1) * N_EDGES;
    int i = blockIdx.x * blockDim.x + threadIdx.x;
    if (i < N_EDGES) {
        int d = dstp[i];
        int pos = rowptr[t * N_NODES + d] + atomicAdd(&cursor[t * N_NODES + d], 1);
        csr_src[t * N_EDGES + pos] = srcp[i];
    }
}

// ---- layer-1 fused: wave per (node,t), online softmax lane-parallel over edges,
//      weighted feature pass with lane=feature (bf16 rows), block combines 4 t's.
__global__ __launch_bounds__(256) void k_agg1(
    const __hip_bfloat16* __restrict__ ft_all, const float* __restrict__ el1,
    const float* __restrict__ er1, const int* __restrict__ rowptr,
    const int* __restrict__ deg, const int* __restrict__ csr_src,
    const float* __restrict__ b1, float* __restrict__ h1) {
    __shared__ float red[4][HID_F];
    int n = blockIdx.x;
    int t = threadIdx.x >> 6;
    int lane = threadIdx.x & 63;
    int beg = rowptr[t * N_NODES + n], cnt = deg[t * N_NODES + n];
    float ern = er1[t * N_NODES + n];
    const int* cs = csr_src + t * N_EDGES;
    const float* el = el1 + t * N_NODES;
    const __hip_bfloat16* ft = ft_all + (long)t * N_NODES * HID_F;
    float acc = 0.f, m_run = -INFINITY, s_run = 0.f;
    for (int c0 = 0; c0 < cnt; c0 += 64) {
        bool valid = (c0 + lane) < cnt;
        int s = valid ? cs[beg + c0 + lane] : 0;
        float e = valid ? lrelu(el[s] + ern) : -INFINITY;
        float cm = wred_max(e);
        float m_new = fmaxf(m_run, cm);
        float scale = (m_run == -INFINITY) ? 0.f : __expf(m_run - m_new);
        float p = valid ? __expf(e - m_new) : 0.f;
        float ps = wred_sum(p);
        s_run = s_run * scale + ps;
        acc *= scale;
        int cn = min(64, cnt - c0);
#pragma unroll 4
        for (int j = 0; j < cn; j++) {
            float pj = __shfl(p, j);
            int sj = __shfl(s, j);
            acc += pj * __bfloat162float(ft[sj * HID_F + lane]);
        }
        m_run = m_new;
    }
    red[t][lane] = (cnt > 0) ? acc / s_run : 0.f;
    __syncthreads();
    if (t == 0) {
        float b = 0.25f * (b1[lane] + b1[HID_F + lane] + b1[2 * HID_F + lane] + b1[3 * HID_F + lane]);
        h1[n * HID_F + lane] = 0.25f * (red[0][lane] + red[1][lane] + red[2][lane] + red[3][lane]) + b;
    }
}

// ---- layer-2 featurization (unchanged, f32 feat2)
__global__ __launch_bounds__(256) void k_feat2(
    const float* __restrict__ h1, const float* __restrict__ W2,
    const float* __restrict__ al2, const float* __restrict__ ar2,
    float* __restrict__ feat2, float* __restrict__ el2, float* __restrict__ er2) {
    __shared__ float Wl[T_G * HID_F * OUT_F];
    __shared__ float Al[T_G * OUT_F], Ar[T_G * OUT_F];
    for (int i = threadIdx.x; i < T_G * HID_F * OUT_F; i += 256) Wl[i] = W2[i];
    if (threadIdx.x < T_G * OUT_F) { Al[threadIdx.x] = al2[threadIdx.x]; Ar[threadIdx.x] = ar2[threadIdx.x]; }
    __syncthreads();
    int n = blockIdx.x * 256 + threadIdx.x;
    if (n >= N_NODES) return;
    float h[HID_F];
    const float4* hp = (const float4*)(h1 + n * HID_F);
#pragma unroll
    for (int i = 0; i < 16; i++) {
        float4 v = hp[i];
        h[4 * i] = v.x; h[4 * i + 1] = v.y; h[4 * i + 2] = v.z; h[4 * i + 3] = v.w;
    }
    for (int t = 0; t < T_G; t++) {
        float f0 = 0.f, f1 = 0.f, f2 = 0.f;
#pragma unroll
        for (int k = 0; k < HID_F; k++) {
            float hv = h[k];
            f0 += hv * Wl[(t * HID_F + k) * 3 + 0];
            f1 += hv * Wl[(t * HID_F + k) * 3 + 1];
            f2 += hv * Wl[(t * HID_F + k) * 3 + 2];
        }
        int ob = (t * N_NODES + n) * 3;
        feat2[ob] = f0; feat2[ob + 1] = f1; feat2[ob + 2] = f2;
        el2[t * N_NODES + n] = f0 * Al[t * 3] + f1 * Al[t * 3 + 1] + f2 * Al[t * 3 + 2];
        er2[t * N_NODES + n] = f0 * Ar[t * 3] + f1 * Ar[t * 3 + 1] + f2 * Ar[t * 3 + 2];
    }
}

// ---- d=3 aggregation: wave per (node,t); fully lane-parallel online softmax;
//      fused combine via atomicAdd into pre-biased hout.
__global__ __launch_bounds__(256) void k_agg3(
    const float* __restrict__ ft_all, const float* __restrict__ el_, const float* __restrict__ er_,
    const int* __restrict__ rowptr, const int* __restrict__ deg, const int* __restrict__ csr_src,
    const float* __restrict__ wv, float* __restrict__ hout) {
    int n = blockIdx.x;
    int t = threadIdx.x >> 6;
    int lane = threadIdx.x & 63;
    int beg = rowptr[t * N_NODES + n], cnt = deg[t * N_NODES + n];
    if (cnt == 0) return;
    float ern = er_[t * N_NODES + n];
    const int* cs = csr_src + t * N_EDGES;
    const float* el = el_ + t * N_NODES;
    const float* ft = ft_all + (long)t * N_NODES * 3;
    float a0 = 0.f, a1 = 0.f, a2 = 0.f, m_run = -INFINITY, s_run = 0.f;
    for (int c0 = 0; c0 < cnt; c0 += 64) {
        bool valid = (c0 + lane) < cnt;
        int s = valid ? cs[beg + c0 + lane] : 0;
        float e = valid ? lrelu(el[s] + ern) : -INFINITY;
        float cm = wred_max(e);
        float m_new = fmaxf(m_run, cm);
        float scale = (m_run == -INFINITY) ? 0.f : __expf(m_run - m_new);
        float p = valid ? __expf(e - m_new) : 0.f;
        float ps = wred_sum(p);
        s_run = s_run * scale + ps;
        a0 = a0 * scale + p * ft[s * 3 + 0];
        a1 = a1 * scale + p * ft[s * 3 + 1];
        a2 = a2 * scale + p * ft[s * 3 + 2];
        m_run = m_new;
    }
    a0 = wred_sum(a0); a1 = wred_sum(a1); a2 = wred_sum(a2);
    float wt = wv[t] / s_run;
    if (lane < 3) {
        float v = (lane == 0) ? a0 : (lane == 1) ? a1 : a2;
        atomicAdd(&hout[n * 3 + lane], wt * v);
    }
}

// ---- layer-3 featurization (3->3)
__global__ void k_feat3(const float* __restrict__ h2, const float* __restrict__ W3,
                        const float* __restrict__ al3, const float* __restrict__ ar3,
                        float* __restrict__ feat3, float* __restrict__ el3, float* __restrict__ er3) {
    int n = blockIdx.x * 256 + threadIdx.x;
    if (n >= N_NODES) return;
    float h0 = h2[n * 3], h1v = h2[n * 3 + 1], h2v = h2[n * 3 + 2];
    for (int t = 0; t < T_G; t++) {
        float el = 0.f, er = 0.f;
#pragma unroll
        for (int d = 0; d < 3; d++) {
            float f = h0 * W3[(t * 3 + 0) * 3 + d] + h1v * W3[(t * 3 + 1) * 3 + d] + h2v * W3[(t * 3 + 2) * 3 + d];
            feat3[(t * N_NODES + n) * 3 + d] = f;
            el += f * al3[t * 3 + d];
            er += f * ar3[t * 3 + d];
        }
        el3[t * N_NODES + n] = el;
        er3[t * N_NODES + n] = er;
    }
}

// ---- layer-M featurization (3 -> 8 heads x 3), bf16 featM
__global__ void k_featM(const float* __restrict__ h3, const float* __restrict__ WM,
                        const float* __restrict__ alM, const float* __restrict__ arM,
                        __hip_bfloat16* __restrict__ featM, float* __restrict__ elM,
                        float* __restrict__ erM) {
    int n = blockIdx.x * 256 + threadIdx.x;
    if (n >= N_NODES) return;
    float h0 = h3[n * 3], h1v = h3[n * 3 + 1], h2v = h3[n * 3 + 2];
    for (int t = 0; t < T_G; t++) {
#pragma unroll
        for (int hh = 0; hh < H_M; hh++) {
            float el = 0.f, er = 0.f;
#pragma unroll
            for (int d = 0; d < 3; d++) {
                int j = hh * 3 + d;
                float f = h0 * WM[(t * 3 + 0) * 24 + j] + h1v * WM[(t * 3 + 1) * 24 + j] + h2v * WM[(t * 3 + 2) * 24 + j];
                featM[(t * N_NODES + n) * 24 + j] = __float2bfloat16(f);
                el += f * alM[(t * H_M + hh) * 3 + d];
                er += f * arM[(t * H_M + hh) * 3 + d];
            }
            elM[(t * N_NODES + n) * 8 + hh] = el;
            erM[(t * N_NODES + n) * 8 + hh] = er;
        }
    }
}

// ---- layer-M softmax stats: wave per (node,t); lane = (edge-octet, head);
//      online max/sum, 3-level shfl reduce (offsets 8/16/32 keep head fixed)
__global__ __launch_bounds__(256) void k_wM(
    const float* __restrict__ elM, const float* __restrict__ erM,
    const int* __restrict__ rowptr, const int* __restrict__ deg, const int* __restrict__ csr_src,
    float* __restrict__ mM, float* __restrict__ invM) {
    int n = blockIdx.x;
    int t = threadIdx.x >> 6;
    int lane = threadIdx.x & 63;
    int h = lane & 7, eo = lane >> 3;
    int beg = rowptr[t * N_NODES + n], cnt = deg[t * N_NODES + n];
    float erh = erM[(t * N_NODES + n) * 8 + h];
    const int* cs = csr_src + t * N_EDGES;
    float m_run = -INFINITY, s_run = 0.f;
    for (int c0 = 0; c0 < cnt; c0 += 8) {
        bool valid = (c0 + eo) < cnt;
        int s = valid ? cs[beg + c0 + eo] : 0;
        float e = valid ? lrelu(elM[(t * N_NODES + s) * 8 + h] + erh) : -INFINITY;
        float cm = e;
#pragma unroll
        for (int o = 8; o < 64; o <<= 1) cm = fmaxf(cm, __shfl_xor(cm, o));
        float m_new = fmaxf(m_run, cm);
        float scale = (m_run == -INFINITY) ? 0.f : __expf(m_run - m_new);
        float p = valid ? __expf(e - m_new) : 0.f;
        float ps = p;
#pragma unroll
        for (int o = 8; o < 64; o <<= 1) ps += __shfl_xor(ps, o);
        s_run = s_run * scale + ps;
        m_run = m_new;
    }
    if (eo == 0) {
        int idx = (t * N_NODES + n) * 8 + h;
        mM[idx] = (cnt > 0) ? m_run : 0.f;
        invM[idx] = (cnt > 0) ? 1.f / s_run : 0.f;
    }
}

// ---- layer-M aggregation: wave per (node,t), lane = output j (24 active);
//      single pass, exp recomputed; fused combine via atomicAdd into pre-biased hM
__global__ __launch_bounds__(256) void k_aggM(
    const __hip_bfloat16* __restrict__ fM, const float* __restrict__ elM,
    const float* __restrict__ erM, const float* __restrict__ mM, const float* __restrict__ invM,
    const int* __restrict__ rowptr, const int* __restrict__ deg, const int* __restrict__ csr_src,
    const float* __restrict__ wv, float* __restrict__ hM) {
    int n = blockIdx.x;
    int t = threadIdx.x >> 6;
    int lane = threadIdx.x & 63;
    int beg = rowptr[t * N_NODES + n], cnt = deg[t * N_NODES + n];
    if (cnt == 0) return;
    int j = (lane < 24) ? lane : 0;
    int h = j / 3;
    int nb = (t * N_NODES + n) * 8 + h;
    float erh = erM[nb], mh = mM[nb], invh = invM[nb];
    const int* cs = csr_src + t * N_EDGES;
    float acc = 0.f;
    for (int pos = beg; pos < beg + cnt; pos++) {
        int s = cs[pos];
        float el = elM[(t * N_NODES + s) * 8 + h];
        float p = __expf(lrelu(el + erh) - mh);
        float f = __bfloat162float(fM[(t * N_NODES + s) * 24 + j]);
        acc += p * f;
    }
    if (lane < 24) atomicAdd(&hM[n * 24 + lane], wv[t] * invh * acc);
}

// ---- delta norms per head
__global__ void k_norms(const float* __restrict__ hM, float* __restrict__ norms) {
    int idx = blockIdx.x * 256 + threadIdx.x;
    if (idx >= N_NODES * H_M) return;
    int n = idx >> 3, hh = idx & 7;
    float s = 0.f;
#pragma unroll
    for (int d = 0; d < 3; d++) {
        float cur = hM[n * 24 + hh * 3 + d];
        float prev = (n > 0) ? hM[(n - 1) * 24 + hh * 3 + d] : 0.f;
        float dx = cur - prev;
        s += dx * dx;
    }
    norms[hh * N_NODES + n] = sqrtf(s);
}

// ---- exact median via radix select
__global__ __launch_bounds__(256) void k_median(const float* __restrict__ norms, float* __restrict__ med) {
    int hh = blockIdx.x;
    const float* v = norms + hh * N_NODES;
    __shared__ unsigned int hist[256];
    __shared__ unsigned int s_sel, s_rank;
    float res[2];
    for (int kk = 0; kk < 2; kk++) {
        unsigned int prefix = 0;
        unsigned int rank = N_NODES / 2 - 1 + kk;
        for (int byte = 3; byte >= 0; byte--) {
            hist[threadIdx.x] = 0;
            __syncthreads();
            unsigned int shift = byte * 8;
            unsigned int maskU = (byte == 3) ? 0u : (0xFFFFFFFFu << (shift + 8));
            for (int i = threadIdx.x; i < N_NODES; i += 256) {
                unsigned int u = __float_as_uint(v[i]);
                if ((u & maskU) == prefix) atomicAdd(&hist[(u >> shift) & 255u], 1u);
            }
            __syncthreads();
            if (threadIdx.x == 0) {
                unsigned int accu = 0;
                for (int b = 0; b < 256; b++) {
                    unsigned int c = hist[b];
                    if (accu + c > rank) { s_sel = prefix | ((unsigned)b << shift); s_rank = rank - accu; break; }
                    accu += c;
                }
            }
            __syncthreads();
            prefix = s_sel;
            rank = s_rank;
            __syncthreads();
        }
        res[kk] = __uint_as_float(prefix);
    }
    if (threadIdx.x == 0) med[hh] = 0.5f * (res[0] + res[1]) + 1e-4f;
}

// ---- final
__global__ void k_final(const float* __restrict__ hM, const float* __restrict__ med,
                        const float* __restrict__ noise, float* __restrict__ out) {
    int idx = blockIdx.x * 256 + threadIdx.x;
    if (idx >= N_NODES * 24) return;
    int hh = (idx / 3) & 7;
    float v = hM[idx] / med[hh];
    if (isnan(v)) v = 0.f;
    else if (isinf(v)) v = v > 0.f ? 100.f : -100.f;
    out[idx] = v + 0.3f * noise[idx];
}

extern "C" void kernel_launch(void* const* d_in, const int* in_sizes, int n_in,
                              void* d_out, int out_size, void* d_ws, size_t ws_size,
                              hipStream_t stream) {
    const float* x     = (const float*)d_in[0];
    const int*   edges = (const int*)d_in[1];
    const float* noise = (const float*)d_in[2];
    const float* W1  = (const float*)d_in[3];
    const float* al1 = (const float*)d_in[4];
    const float* ar1 = (const float*)d_in[5];
    const float* b1  = (const float*)d_in[6];
    const float* W2  = (const float*)d_in[7];
    const float* al2 = (const float*)d_in[8];
    const float* ar2 = (const float*)d_in[9];
    const float* b2  = (const float*)d_in[10];
    const float* W3  = (const float*)d_in[11];
    const float* al3 = (const float*)d_in[12];
    const float* ar3 = (const float*)d_in[13];
    const float* b3  = (const float*)d_in[14];
    const float* WM  = (const float*)d_in[15];
    const float* alM = (const float*)d_in[16];
    const float* arM = (const float*)d_in[17];
    const float* bM  = (const float*)d_in[18];
    const float* fc2 = (const float*)d_in[19];
    const float* fc3 = (const float*)d_in[20];
    float* out = (float*)d_out;

    char* basep = (char*)d_ws;
    size_t off = 0;
    auto alloc = [&](size_t bytes) -> void* {
        void* p = basep + off;
        off += (bytes + 255) & ~(size_t)255;
        return p;
    };
    // Region A: feat1 bf16 (T*N*64*2 = 25.6 MB); reused after k_agg1 for featM/elM/erM
    char* regA = (char*)alloc((size_t)T_G * N_NODES * HID_F * 2);
    __hip_bfloat16* feat1 = (__hip_bfloat16*)regA;
    __hip_bfloat16* featM = (__hip_bfloat16*)regA;                       // T*N*24*2 = 9.6 MB
    float* elM = (float*)(regA + 9600000);                               // 6.4 MB
    float* erM = (float*)(regA + 16000000);                              // 6.4 MB
    float* el1 = (float*)alloc((size_t)T_G * N_NODES * 4);
    float* er1 = (float*)alloc((size_t)T_G * N_NODES * 4);
    float* h1  = (float*)alloc((size_t)N_NODES * HID_F * 4);
    float* feat2 = (float*)alloc((size_t)T_G * N_NODES * 3 * 4);
    float* el2 = (float*)alloc((size_t)T_G * N_NODES * 4);
    float* er2 = (float*)alloc((size_t)T_G * N_NODES * 4);
    float* h2  = (float*)alloc((size_t)N_NODES * 3 * 4);
    float* feat3 = (float*)alloc((size_t)T_G * N_NODES * 3 * 4);
    float* el3 = (float*)alloc((size_t)T_G * N_NODES * 4);
    float* er3 = (float*)alloc((size_t)T_G * N_NODES * 4);
    float* h3  = (float*)alloc((size_t)N_NODES * 3 * 4);
    float* mM   = (float*)alloc((size_t)T_G * N_NODES * 8 * 4);
    float* invM = (float*)alloc((size_t)T_G * N_NODES * 8 * 4);
    float* hM  = (float*)alloc((size_t)N_NODES * 24 * 4);
    float* norms = (float*)alloc((size_t)H_M * N_NODES * 4);
    float* med = (float*)alloc(64);
    float* wbuf = (float*)alloc(256);
    int* deg    = (int*)alloc((size_t)T_G * N_NODES * 4);
    int* cursor = (int*)alloc((size_t)T_G * N_NODES * 4);
    int* rowptr = (int*)alloc((size_t)T_G * N_NODES * 4);
    int* csr_src = (int*)alloc((size_t)T_G * N_EDGES * 4);

    const int NB = (N_NODES + 255) / 256;

    hipMemsetAsync(deg, 0, (size_t)T_G * N_NODES * 4, stream);
    hipMemsetAsync(cursor, 0, (size_t)T_G * N_NODES * 4, stream);

    k_wvec<<<1, 64, 0, stream>>>(fc2, fc3, b2, b3, bM, wbuf);

    // CSR build
    k_count<<<dim3(N_EDGES / 256, T_G), 256, 0, stream>>>(edges, deg);
    k_scan<<<T_G, 1024, 0, stream>>>(deg, rowptr);
    k_scatter<<<dim3(N_EDGES / 256, T_G), 256, 0, stream>>>(edges, rowptr, cursor, csr_src);

    // Layer 1
    k_gemm1<<<dim3(N_NODES / 16, T_G), 256, 0, stream>>>(x, W1, al1, ar1, feat1, el1, er1);
    k_agg1<<<N_NODES, 256, 0, stream>>>(feat1, el1, er1, rowptr, deg, csr_src, b1, h1);

    // Layer 2
    k_feat2<<<NB, 256, 0, stream>>>(h1, W2, al2, ar2, feat2, el2, er2);
    k_initrep<<<(N_NODES * 3 + 255) / 256, 256, 0, stream>>>(h2, N_NODES * 3, wbuf + 8, 3);
    k_agg3<<<N_NODES, 256, 0, stream>>>(feat2, el2, er2, rowptr, deg, csr_src, wbuf + 0, h2);

    // Layer 3
    k_feat3<<<NB, 256, 0, stream>>>(h2, W3, al3, ar3, feat3, el3, er3);
    k_initrep<<<(N_NODES * 3 + 255) / 256, 256, 0, stream>>>(h3, N_NODES * 3, wbuf + 11, 3);
    k_agg3<<<N_NODES, 256, 0, stream>>>(feat3, el3, er3, rowptr, deg, csr_src, wbuf + 4, h3);

    // Layer M (region A reuse: feat1 dead after k_agg1)
    k_featM<<<NB, 256, 0, stream>>>(h3, WM, alM, arM, featM, elM, erM);
    k_wM<<<N_NODES, 256, 0, stream>>>(elM, erM, rowptr, deg, csr_src, mM, invM);
    k_initrep<<<(N_NODES * 24 + 255) / 256, 256, 0, stream>>>(hM, N_NODES * 24, wbuf + 16, 24);
    k_aggM<<<N_NODES, 256, 0, stream>>>(featM, elM, erM, mM, invM, rowptr, deg, csr_src, wbuf + 4, hM);

    // norm_ (telescoped) + output
    k_norms<<<(N_NODES * H_M + 255) / 256, 256, 0, stream>>>(hM, norms);
    k_median<<<H_M, 256, 0, stream>>>(norms, med);
    k_final<<<(N_NODES * 24 + 255) / 256, 256, 0, stream>>>(hM, med, noise, out);
}

// Round 3
// 1373.924 us; speedup vs baseline: 1.2747x; 1.2027x over previous
//
#include <hip/hip_runtime.h>
#include <hip/hip_bf16.h>
#include <math.h>

#define N_NODES 50000
#define N_EDGES 800000
#define T_G 4
#define IN_F 128
#define HID_F 64
#define OUT_F 3
#define H_M 8

__device__ __forceinline__ float lrelu(float v) { return v > 0.f ? v : 0.2f * v; }

__device__ __forceinline__ float wred_max(float v) {
#pragma unroll
    for (int o = 32; o; o >>= 1) v = fmaxf(v, __shfl_xor(v, o));
    return v;
}
__device__ __forceinline__ float wred_sum(float v) {
#pragma unroll
    for (int o = 32; o; o >>= 1) v += __shfl_xor(v, o);
    return v;
}

// ---- weight/bias precompute:
// w[0:4]=w2, [4:8]=w3, [8:11]=cb2, [11:14]=cb3, [16:40]=cbM, [64:128]=bavg1
__global__ void k_wvec(const float* __restrict__ fc2, const float* __restrict__ fc3,
                       const float* __restrict__ b1, const float* __restrict__ b2,
                       const float* __restrict__ b3, const float* __restrict__ bM,
                       float* __restrict__ w) {
    __shared__ float w2[4], w3[4];
    int i = threadIdx.x;
    if (i < 4) {
        float a = 0.f, b = 0.f;
        for (int r = 0; r < T_G; r++) { a += fc2[r * T_G + i]; b += fc3[r * T_G + i]; }
        w2[i] = 0.25f * a; w3[i] = 0.25f * b;
        w[i] = w2[i]; w[4 + i] = w3[i];
    }
    __syncthreads();
    if (i < 3) {
        float c = 0.f;
        for (int t = 0; t < T_G; t++) c += w2[t] * b2[t * 3 + i];
        w[8 + i] = c;
    }
    if (i >= 8 && i < 11) {
        int d = i - 8;
        float c = 0.f;
        for (int t = 0; t < T_G; t++) c += w3[t] * b3[t * 3 + d];
        w[11 + d] = c;
    }
    if (i >= 16 && i < 40) {
        int j = i - 16;
        float c = 0.f;
        for (int t = 0; t < T_G; t++) c += w3[t] * bM[t * 24 + j];
        w[16 + j] = c;
    }
    if (i >= 64 && i < 128) {
        int c = i - 64;
        w[i] = 0.25f * (b1[c] + b1[HID_F + c] + b1[2 * HID_F + c] + b1[3 * HID_F + c]);
    }
}

__global__ void k_initrep(float* __restrict__ dst, int n, const float* __restrict__ src, int period) {
    int i = blockIdx.x * 256 + threadIdx.x;
    if (i < n) dst[i] = src[i % period];
}

// ---- layer-1 GEMM: feat1(bf16)[t,n,c], el1/er1
__global__ __launch_bounds__(256) void k_gemm1(
    const float* __restrict__ x, const float* __restrict__ W1,
    const float* __restrict__ al1, const float* __restrict__ ar1,
    __hip_bfloat16* __restrict__ feat1, float* __restrict__ el1, float* __restrict__ er1) {
    __shared__ float Wl[IN_F * HID_F];
    __shared__ float Xl[16 * IN_F];
    int t = blockIdx.y;
    int base = blockIdx.x * 16;
    for (int i = threadIdx.x; i < IN_F * HID_F; i += 256) Wl[i] = W1[t * IN_F * HID_F + i];
    for (int i = threadIdx.x; i < 16 * IN_F; i += 256) Xl[i] = x[base * IN_F + i];
    __syncthreads();
    int c = threadIdx.x & 63;
    int rq = threadIdx.x >> 6;
    float acc[4] = {0.f, 0.f, 0.f, 0.f};
    for (int k = 0; k < IN_F; k++) {
        float w = Wl[k * HID_F + c];
#pragma unroll
        for (int i = 0; i < 4; i++) acc[i] += Xl[(rq * 4 + i) * IN_F + k] * w;
    }
    float alv = al1[t * HID_F + c], arv = ar1[t * HID_F + c];
#pragma unroll
    for (int i = 0; i < 4; i++) {
        int row = base + rq * 4 + i;
        feat1[(t * N_NODES + row) * HID_F + c] = __float2bfloat16(acc[i]);
        float vl = acc[i] * alv, vr = acc[i] * arv;
#pragma unroll
        for (int off = 32; off; off >>= 1) { vl += __shfl_xor(vl, off); vr += __shfl_xor(vr, off); }
        if (c == 0) { el1[t * N_NODES + row] = vl; er1[t * N_NODES + row] = vr; }
    }
}

// ---- CSR build
__global__ void k_count(const int* __restrict__ edges, int* __restrict__ deg) {
    int t = blockIdx.y;
    const int* dst = edges + (t * 2 + 1) * N_EDGES;
    int i = blockIdx.x * blockDim.x + threadIdx.x;
    if (i < N_EDGES) atomicAdd(&deg[t * N_NODES + dst[i]], 1);
}

// 3-phase parallel exclusive scan of deg -> rowptr
__global__ __launch_bounds__(1024) void k_scan1(const int* __restrict__ deg,
                                                int* __restrict__ rowptr, int* __restrict__ bsum) {
    int t = blockIdx.y, b = blockIdx.x;
    int i = b * 1024 + threadIdx.x;
    int lane = threadIdx.x & 63, wid = threadIdx.x >> 6;
    int v = (i < N_NODES) ? deg[t * N_NODES + i] : 0;
    int sc = v;
#pragma unroll
    for (int o = 1; o < 64; o <<= 1) { int u = __shfl_up(sc, o); if (lane >= o) sc += u; }
    __shared__ int ws[16];
    if (lane == 63) ws[wid] = sc;
    __syncthreads();
    if (wid == 0 && lane < 16) {
        int wv = ws[lane];
#pragma unroll
        for (int o = 1; o < 16; o <<= 1) { int u = __shfl_up(wv, o); if (lane >= o) wv += u; }
        ws[lane] = wv;
    }
    __syncthreads();
    int woff = (wid == 0) ? 0 : ws[wid - 1];
    if (i < N_NODES) rowptr[t * N_NODES + i] = woff + sc - v;  // exclusive (block-local)
    if (threadIdx.x == 1023) bsum[t * 64 + b] = woff + sc;     // block total
}

__global__ void k_scan2(int* __restrict__ bsum) {
    int t = threadIdx.x >> 6, lane = threadIdx.x & 63;
    int v = (lane < 49) ? bsum[t * 64 + lane] : 0;
    int sc = v;
#pragma unroll
    for (int o = 1; o < 64; o <<= 1) { int u = __shfl_up(sc, o); if (lane >= o) sc += u; }
    if (lane < 49) bsum[t * 64 + lane] = sc - v;  // exclusive
}

__global__ __launch_bounds__(1024) void k_scan3(int* __restrict__ rowptr, const int* __restrict__ bsum) {
    int t = blockIdx.y, b = blockIdx.x;
    int i = b * 1024 + threadIdx.x;
    if (i < N_NODES) rowptr[t * N_NODES + i] += bsum[t * 64 + b];
}

__global__ void k_scatter(const int* __restrict__ edges, const int* __restrict__ rowptr,
                          int* __restrict__ cursor, int* __restrict__ csr_src) {
    int t = blockIdx.y;
    const int* srcp = edges + (t * 2 + 0) * N_EDGES;
    const int* dstp = edges + (t * 2 + 1) * N_EDGES;
    int i = blockIdx.x * blockDim.x + threadIdx.x;
    if (i < N_EDGES) {
        int d = dstp[i];
        int pos = rowptr[t * N_NODES + d] + atomicAdd(&cursor[t * N_NODES + d], 1);
        csr_src[t * N_EDGES + pos] = srcp[i];
    }
}

// ---- layer-1 aggregation: blockIdx.y = t (L2 locality), wave per node,
//      online softmax edge-parallel, broadcast-gather 64-col rows, atomicAdd combine.
__global__ __launch_bounds__(256) void k_agg1(
    const __hip_bfloat16* __restrict__ ft_all, const float* __restrict__ el1,
    const float* __restrict__ er1, const int* __restrict__ rowptr,
    const int* __restrict__ deg, const int* __restrict__ csr_src,
    float* __restrict__ h1) {
    int t = blockIdx.y;
    int n = blockIdx.x * 4 + (threadIdx.x >> 6);
    int lane = threadIdx.x & 63;
    int beg = rowptr[t * N_NODES + n], cnt = deg[t * N_NODES + n];
    if (cnt == 0) return;  // h1 pre-biased
    float ern = er1[t * N_NODES + n];
    const int* cs = csr_src + t * N_EDGES;
    const float* el = el1 + t * N_NODES;
    const __hip_bfloat16* ft = ft_all + (long)t * N_NODES * HID_F;
    float acc = 0.f, m_run = -INFINITY, s_run = 0.f;
    for (int c0 = 0; c0 < cnt; c0 += 64) {
        bool valid = (c0 + lane) < cnt;
        int s = valid ? cs[beg + c0 + lane] : 0;
        float e = valid ? lrelu(el[s] + ern) : -INFINITY;
        float cm = wred_max(e);
        float m_new = fmaxf(m_run, cm);
        float scale = (m_run == -INFINITY) ? 0.f : __expf(m_run - m_new);
        float p = valid ? __expf(e - m_new) : 0.f;
        float ps = wred_sum(p);
        s_run = s_run * scale + ps;
        acc *= scale;
        int cn = min(64, cnt - c0);
#pragma unroll 4
        for (int j = 0; j < cn; j++) {
            float pj = __shfl(p, j);
            int sj = __shfl(s, j);
            acc += pj * __bfloat162float(ft[sj * HID_F + lane]);
        }
        m_run = m_new;
    }
    atomicAdd(&h1[n * HID_F + lane], 0.25f * acc / s_run);
}

// ---- layer-2 featurization
__global__ __launch_bounds__(256) void k_feat2(
    const float* __restrict__ h1, const float* __restrict__ W2,
    const float* __restrict__ al2, const float* __restrict__ ar2,
    float* __restrict__ feat2, float* __restrict__ el2, float* __restrict__ er2) {
    __shared__ float Wl[T_G * HID_F * OUT_F];
    __shared__ float Al[T_G * OUT_F], Ar[T_G * OUT_F];
    for (int i = threadIdx.x; i < T_G * HID_F * OUT_F; i += 256) Wl[i] = W2[i];
    if (threadIdx.x < T_G * OUT_F) { Al[threadIdx.x] = al2[threadIdx.x]; Ar[threadIdx.x] = ar2[threadIdx.x]; }
    __syncthreads();
    int n = blockIdx.x * 256 + threadIdx.x;
    if (n >= N_NODES) return;
    float h[HID_F];
    const float4* hp = (const float4*)(h1 + n * HID_F);
#pragma unroll
    for (int i = 0; i < 16; i++) {
        float4 v = hp[i];
        h[4 * i] = v.x; h[4 * i + 1] = v.y; h[4 * i + 2] = v.z; h[4 * i + 3] = v.w;
    }
    for (int t = 0; t < T_G; t++) {
        float f0 = 0.f, f1 = 0.f, f2 = 0.f;
#pragma unroll
        for (int k = 0; k < HID_F; k++) {
            float hv = h[k];
            f0 += hv * Wl[(t * HID_F + k) * 3 + 0];
            f1 += hv * Wl[(t * HID_F + k) * 3 + 1];
            f2 += hv * Wl[(t * HID_F + k) * 3 + 2];
        }
        int ob = (t * N_NODES + n) * 3;
        feat2[ob] = f0; feat2[ob + 1] = f1; feat2[ob + 2] = f2;
        el2[t * N_NODES + n] = f0 * Al[t * 3] + f1 * Al[t * 3 + 1] + f2 * Al[t * 3 + 2];
        er2[t * N_NODES + n] = f0 * Ar[t * 3] + f1 * Ar[t * 3 + 1] + f2 * Ar[t * 3 + 2];
    }
}

// ---- d=3 aggregation: blockIdx.y = t, wave per node, lane-parallel online softmax,
//      fused combine via atomicAdd into pre-biased hout.
__global__ __launch_bounds__(256) void k_agg3(
    const float* __restrict__ ft_all, const float* __restrict__ el_, const float* __restrict__ er_,
    const int* __restrict__ rowptr, const int* __restrict__ deg, const int* __restrict__ csr_src,
    const float* __restrict__ wv, float* __restrict__ hout) {
    int t = blockIdx.y;
    int n = blockIdx.x * 4 + (threadIdx.x >> 6);
    int lane = threadIdx.x & 63;
    int beg = rowptr[t * N_NODES + n], cnt = deg[t * N_NODES + n];
    if (cnt == 0) return;
    float ern = er_[t * N_NODES + n];
    const int* cs = csr_src + t * N_EDGES;
    const float* el = el_ + t * N_NODES;
    const float* ft = ft_all + (long)t * N_NODES * 3;
    float a0 = 0.f, a1 = 0.f, a2 = 0.f, m_run = -INFINITY, s_run = 0.f;
    for (int c0 = 0; c0 < cnt; c0 += 64) {
        bool valid = (c0 + lane) < cnt;
        int s = valid ? cs[beg + c0 + lane] : 0;
        float e = valid ? lrelu(el[s] + ern) : -INFINITY;
        float cm = wred_max(e);
        float m_new = fmaxf(m_run, cm);
        float scale = (m_run == -INFINITY) ? 0.f : __expf(m_run - m_new);
        float p = valid ? __expf(e - m_new) : 0.f;
        float ps = wred_sum(p);
        s_run = s_run * scale + ps;
        a0 = a0 * scale + p * ft[s * 3 + 0];
        a1 = a1 * scale + p * ft[s * 3 + 1];
        a2 = a2 * scale + p * ft[s * 3 + 2];
        m_run = m_new;
    }
    a0 = wred_sum(a0); a1 = wred_sum(a1); a2 = wred_sum(a2);
    float wt = wv[t] / s_run;
    if (lane < 3) {
        float v = (lane == 0) ? a0 : (lane == 1) ? a1 : a2;
        atomicAdd(&hout[n * 3 + lane], wt * v);
    }
}

// ---- layer-3 featurization (3->3)
__global__ void k_feat3(const float* __restrict__ h2, const float* __restrict__ W3,
                        const float* __restrict__ al3, const float* __restrict__ ar3,
                        float* __restrict__ feat3, float* __restrict__ el3, float* __restrict__ er3) {
    int n = blockIdx.x * 256 + threadIdx.x;
    if (n >= N_NODES) return;
    float h0 = h2[n * 3], h1v = h2[n * 3 + 1], h2v = h2[n * 3 + 2];
    for (int t = 0; t < T_G; t++) {
        float el = 0.f, er = 0.f;
#pragma unroll
        for (int d = 0; d < 3; d++) {
            float f = h0 * W3[(t * 3 + 0) * 3 + d] + h1v * W3[(t * 3 + 1) * 3 + d] + h2v * W3[(t * 3 + 2) * 3 + d];
            feat3[(t * N_NODES + n) * 3 + d] = f;
            el += f * al3[t * 3 + d];
            er += f * ar3[t * 3 + d];
        }
        el3[t * N_NODES + n] = el;
        er3[t * N_NODES + n] = er;
    }
}

// ---- layer-M featurization: packed bf16 row rowM[t][n][32] = {el[0:8], f[0:24]}, er f32
__global__ void k_featM(const float* __restrict__ h3, const float* __restrict__ WM,
                        const float* __restrict__ alM, const float* __restrict__ arM,
                        __hip_bfloat16* __restrict__ rowM, float* __restrict__ erM) {
    int n = blockIdx.x * 256 + threadIdx.x;
    if (n >= N_NODES) return;
    float h0 = h3[n * 3], h1v = h3[n * 3 + 1], h2v = h3[n * 3 + 2];
    for (int t = 0; t < T_G; t++) {
        long rb = ((long)t * N_NODES + n) * 32;
#pragma unroll
        for (int hh = 0; hh < H_M; hh++) {
            float el = 0.f, er = 0.f;
#pragma unroll
            for (int d = 0; d < 3; d++) {
                int j = hh * 3 + d;
                float f = h0 * WM[(t * 3 + 0) * 24 + j] + h1v * WM[(t * 3 + 1) * 24 + j] + h2v * WM[(t * 3 + 2) * 24 + j];
                rowM[rb + 8 + j] = __float2bfloat16(f);
                el += f * alM[(t * H_M + hh) * 3 + d];
                er += f * arM[(t * H_M + hh) * 3 + d];
            }
            rowM[rb + hh] = __float2bfloat16(el);
            erM[(t * N_NODES + n) * 8 + hh] = er;
        }
    }
}

// ---- layer-M softmax stats: blockIdx.y = t, wave per node, lane = (edge-octet, head)
__global__ __launch_bounds__(256) void k_wM(
    const __hip_bfloat16* __restrict__ rowM, const float* __restrict__ erM,
    const int* __restrict__ rowptr, const int* __restrict__ deg, const int* __restrict__ csr_src,
    float* __restrict__ mM, float* __restrict__ invM) {
    int t = blockIdx.y;
    int n = blockIdx.x * 4 + (threadIdx.x >> 6);
    int lane = threadIdx.x & 63;
    int h = lane & 7, eo = lane >> 3;
    int beg = rowptr[t * N_NODES + n], cnt = deg[t * N_NODES + n];
    float erh = erM[(t * N_NODES + n) * 8 + h];
    const int* cs = csr_src + t * N_EDGES;
    float m_run = -INFINITY, s_run = 0.f;
    for (int c0 = 0; c0 < cnt; c0 += 8) {
        bool valid = (c0 + eo) < cnt;
        int s = valid ? cs[beg + c0 + eo] : 0;
        float elv = __bfloat162float(rowM[((long)t * N_NODES + s) * 32 + h]);
        float e = valid ? lrelu(elv + erh) : -INFINITY;
        float cm = e;
#pragma unroll
        for (int o = 8; o < 64; o <<= 1) cm = fmaxf(cm, __shfl_xor(cm, o));
        float m_new = fmaxf(m_run, cm);
        float scale = (m_run == -INFINITY) ? 0.f : __expf(m_run - m_new);
        float p = valid ? __expf(e - m_new) : 0.f;
        float ps = p;
#pragma unroll
        for (int o = 8; o < 64; o <<= 1) ps += __shfl_xor(ps, o);
        s_run = s_run * scale + ps;
        m_run = m_new;
    }
    if (eo == 0) {
        int idx = (t * N_NODES + n) * 8 + h;
        mM[idx] = (cnt > 0) ? m_run : 0.f;
        invM[idx] = (cnt > 0) ? 1.f / s_run : 0.f;
    }
}

// ---- layer-M aggregation: blockIdx.y = t, wave per node, 2 edges x 24 outputs in flight
__global__ __launch_bounds__(256) void k_aggM(
    const __hip_bfloat16* __restrict__ rowM, const float* __restrict__ erM,
    const float* __restrict__ mM, const float* __restrict__ invM,
    const int* __restrict__ rowptr, const int* __restrict__ deg, const int* __restrict__ csr_src,
    const float* __restrict__ wv, float* __restrict__ hM) {
    int t = blockIdx.y;
    int n = blockIdx.x * 4 + (threadIdx.x >> 6);
    int lane = threadIdx.x & 63;
    int beg = rowptr[t * N_NODES + n], cnt = deg[t * N_NODES + n];
    if (cnt == 0) return;
    int j = lane & 31; if (j > 23) j = 23;  // lanes 24-31/56-63 duplicate, never written
    int eo = lane >> 5;
    int h = j / 3;
    int nb = (t * N_NODES + n) * 8 + h;
    float erh = erM[nb], mh = mM[nb], invh = invM[nb];
    const int* cs = csr_src + t * N_EDGES;
    float acc = 0.f;
    for (int pos = 0; pos < cnt; pos += 2) {
        bool valid = (pos + eo) < cnt;
        int s = cs[beg + pos + (valid ? eo : 0)];
        long rb = ((long)t * N_NODES + s) * 32;
        float elv = __bfloat162float(rowM[rb + h]);
        float f = __bfloat162float(rowM[rb + 8 + j]);
        float p = valid ? __expf(lrelu(elv + erh) - mh) : 0.f;
        acc += p * f;
    }
    acc += __shfl_xor(acc, 32);  // combine edge halves
    if (lane < 24) atomicAdd(&hM[n * 24 + lane], wv[t] * invh * acc);
}

// ---- delta norms per head
__global__ void k_norms(const float* __restrict__ hM, float* __restrict__ norms) {
    int idx = blockIdx.x * 256 + threadIdx.x;
    if (idx >= N_NODES * H_M) return;
    int n = idx >> 3, hh = idx & 7;
    float s = 0.f;
#pragma unroll
    for (int d = 0; d < 3; d++) {
        float cur = hM[n * 24 + hh * 3 + d];
        float prev = (n > 0) ? hM[(n - 1) * 24 + hh * 3 + d] : 0.f;
        float dx = cur - prev;
        s += dx * dx;
    }
    norms[hh * N_NODES + n] = sqrtf(s);
}

// ---- exact median via radix select
__global__ __launch_bounds__(256) void k_median(const float* __restrict__ norms, float* __restrict__ med) {
    int hh = blockIdx.x;
    const float* v = norms + hh * N_NODES;
    __shared__ unsigned int hist[256];
    __shared__ unsigned int s_sel, s_rank;
    float res[2];
    for (int kk = 0; kk < 2; kk++) {
        unsigned int prefix = 0;
        unsigned int rank = N_NODES / 2 - 1 + kk;
        for (int byte = 3; byte >= 0; byte--) {
            hist[threadIdx.x] = 0;
            __syncthreads();
            unsigned int shift = byte * 8;
            unsigned int maskU = (byte == 3) ? 0u : (0xFFFFFFFFu << (shift + 8));
            for (int i = threadIdx.x; i < N_NODES; i += 256) {
                unsigned int u = __float_as_uint(v[i]);
                if ((u & maskU) == prefix) atomicAdd(&hist[(u >> shift) & 255u], 1u);
            }
            __syncthreads();
            if (threadIdx.x == 0) {
                unsigned int accu = 0;
                for (int b = 0; b < 256; b++) {
                    unsigned int c = hist[b];
                    if (accu + c > rank) { s_sel = prefix | ((unsigned)b << shift); s_rank = rank - accu; break; }
                    accu += c;
                }
            }
            __syncthreads();
            prefix = s_sel;
            rank = s_rank;
            __syncthreads();
        }
        res[kk] = __uint_as_float(prefix);
    }
    if (threadIdx.x == 0) med[hh] = 0.5f * (res[0] + res[1]) + 1e-4f;
}

// ---- final
__global__ void k_final(const float* __restrict__ hM, const float* __restrict__ med,
                        const float* __restrict__ noise, float* __restrict__ out) {
    int idx = blockIdx.x * 256 + threadIdx.x;
    if (idx >= N_NODES * 24) return;
    int hh = (idx / 3) & 7;
    float v = hM[idx] / med[hh];
    if (isnan(v)) v = 0.f;
    else if (isinf(v)) v = v > 0.f ? 100.f : -100.f;
    out[idx] = v + 0.3f * noise[idx];
}

extern "C" void kernel_launch(void* const* d_in, const int* in_sizes, int n_in,
                              void* d_out, int out_size, void* d_ws, size_t ws_size,
                              hipStream_t stream) {
    const float* x     = (const float*)d_in[0];
    const int*   edges = (const int*)d_in[1];
    const float* noise = (const float*)d_in[2];
    const float* W1  = (const float*)d_in[3];
    const float* al1 = (const float*)d_in[4];
    const float* ar1 = (const float*)d_in[5];
    const float* b1  = (const float*)d_in[6];
    const float* W2  = (const float*)d_in[7];
    const float* al2 = (const float*)d_in[8];
    const float* ar2 = (const float*)d_in[9];
    const float* b2  = (const float*)d_in[10];
    const float* W3  = (const float*)d_in[11];
    const float* al3 = (const float*)d_in[12];
    const float* ar3 = (const float*)d_in[13];
    const float* b3  = (const float*)d_in[14];
    const float* WM  = (const float*)d_in[15];
    const float* alM = (const float*)d_in[16];
    const float* arM = (const float*)d_in[17];
    const float* bM  = (const float*)d_in[18];
    const float* fc2 = (const float*)d_in[19];
    const float* fc3 = (const float*)d_in[20];
    float* out = (float*)d_out;

    char* basep = (char*)d_ws;
    size_t off = 0;
    auto alloc = [&](size_t bytes) -> void* {
        void* p = basep + off;
        off += (bytes + 255) & ~(size_t)255;
        return p;
    };
    // Region A: feat1 bf16 (25.6 MB); rowM (12.8 MB) aliases it after k_agg1
    char* regA = (char*)alloc((size_t)T_G * N_NODES * HID_F * 2);
    __hip_bfloat16* feat1 = (__hip_bfloat16*)regA;
    __hip_bfloat16* rowM  = (__hip_bfloat16*)regA;  // T*N*32 bf16
    float* el1 = (float*)alloc((size_t)T_G * N_NODES * 4);
    float* er1 = (float*)alloc((size_t)T_G * N_NODES * 4);
    float* h1  = (float*)alloc((size_t)N_NODES * HID_F * 4);
    float* feat2 = (float*)alloc((size_t)T_G * N_NODES * 3 * 4);
    float* el2 = (float*)alloc((size_t)T_G * N_NODES * 4);
    float* er2 = (float*)alloc((size_t)T_G * N_NODES * 4);
    float* h2  = (float*)alloc((size_t)N_NODES * 3 * 4);
    float* feat3 = (float*)alloc((size_t)T_G * N_NODES * 3 * 4);
    float* el3 = (float*)alloc((size_t)T_G * N_NODES * 4);
    float* er3 = (float*)alloc((size_t)T_G * N_NODES * 4);
    float* h3  = (float*)alloc((size_t)N_NODES * 3 * 4);
    float* erM  = (float*)alloc((size_t)T_G * N_NODES * 8 * 4);
    float* mM   = (float*)alloc((size_t)T_G * N_NODES * 8 * 4);
    float* invM = (float*)alloc((size_t)T_G * N_NODES * 8 * 4);
    float* hM  = (float*)alloc((size_t)N_NODES * 24 * 4);
    float* norms = (float*)alloc((size_t)H_M * N_NODES * 4);
    float* med = (float*)alloc(64);
    float* wbuf = (float*)alloc(512);
    int* deg    = (int*)alloc((size_t)T_G * N_NODES * 4);
    int* cursor = (int*)alloc((size_t)T_G * N_NODES * 4);
    int* rowptr = (int*)alloc((size_t)T_G * N_NODES * 4);
    int* bsum   = (int*)alloc((size_t)T_G * 64 * 4);
    int* csr_src = (int*)alloc((size_t)T_G * N_EDGES * 4);

    const int NB = (N_NODES + 255) / 256;   // 196
    const int NW = (N_NODES + 3) / 4;       // 12500 (wave-per-node grids)
    const int NS = (N_NODES + 1023) / 1024; // 49

    hipMemsetAsync(deg, 0, (size_t)T_G * N_NODES * 4, stream);
    hipMemsetAsync(cursor, 0, (size_t)T_G * N_NODES * 4, stream);

    k_wvec<<<1, 128, 0, stream>>>(fc2, fc3, b1, b2, b3, bM, wbuf);

    // CSR build
    k_count<<<dim3(N_EDGES / 256, T_G), 256, 0, stream>>>(edges, deg);
    k_scan1<<<dim3(NS, T_G), 1024, 0, stream>>>(deg, rowptr, bsum);
    k_scan2<<<1, 256, 0, stream>>>(bsum);
    k_scan3<<<dim3(NS, T_G), 1024, 0, stream>>>(rowptr, bsum);
    k_scatter<<<dim3(N_EDGES / 256, T_G), 256, 0, stream>>>(edges, rowptr, cursor, csr_src);

    // Layer 1
    k_gemm1<<<dim3(N_NODES / 16, T_G), 256, 0, stream>>>(x, W1, al1, ar1, feat1, el1, er1);
    k_initrep<<<(N_NODES * HID_F + 255) / 256, 256, 0, stream>>>(h1, N_NODES * HID_F, wbuf + 64, HID_F);
    k_agg1<<<dim3(NW, T_G), 256, 0, stream>>>(feat1, el1, er1, rowptr, deg, csr_src, h1);

    // Layer 2
    k_feat2<<<NB, 256, 0, stream>>>(h1, W2, al2, ar2, feat2, el2, er2);
    k_initrep<<<(N_NODES * 3 + 255) / 256, 256, 0, stream>>>(h2, N_NODES * 3, wbuf + 8, 3);
    k_agg3<<<dim3(NW, T_G), 256, 0, stream>>>(feat2, el2, er2, rowptr, deg, csr_src, wbuf + 0, h2);

    // Layer 3
    k_feat3<<<NB, 256, 0, stream>>>(h2, W3, al3, ar3, feat3, el3, er3);
    k_initrep<<<(N_NODES * 3 + 255) / 256, 256, 0, stream>>>(h3, N_NODES * 3, wbuf + 11, 3);
    k_agg3<<<dim3(NW, T_G), 256, 0, stream>>>(feat3, el3, er3, rowptr, deg, csr_src, wbuf + 4, h3);

    // Layer M (rowM aliases feat1 region; feat1 dead after k_agg1)
    k_featM<<<NB, 256, 0, stream>>>(h3, WM, alM, arM, rowM, erM);
    k_wM<<<dim3(NW, T_G), 256, 0, stream>>>(rowM, erM, rowptr, deg, csr_src, mM, invM);
    k_initrep<<<(N_NODES * 24 + 255) / 256, 256, 0, stream>>>(hM, N_NODES * 24, wbuf + 16, 24);
    k_aggM<<<dim3(NW, T_G), 256, 0, stream>>>(rowM, erM, mM, invM, rowptr, deg, csr_src, wbuf + 4, hM);

    // norm_ (telescoped) + output
    k_norms<<<(N_NODES * H_M + 255) / 256, 256, 0, stream>>>(hM, norms);
    k_median<<<H_M, 256, 0, stream>>>(norms, med);
    k_final<<<(N_NODES * 24 + 255) / 256, 256, 0, stream>>>(hM, med, noise, out);
}

// Round 4
// 1213.110 us; speedup vs baseline: 1.4437x; 1.1326x over previous
//
#include <hip/hip_runtime.h>
#include <hip/hip_bf16.h>
#include <math.h>

#define N_NODES 50000
#define N_EDGES 800000
#define T_G 4
#define IN_F 128
#define HID_F 64
#define OUT_F 3
#define H_M 8

__device__ __forceinline__ float lrelu(float v) { return v > 0.f ? v : 0.2f * v; }

__device__ __forceinline__ float wred_max(float v) {
#pragma unroll
    for (int o = 32; o; o >>= 1) v = fmaxf(v, __shfl_xor(v, o));
    return v;
}
__device__ __forceinline__ float wred_sum(float v) {
#pragma unroll
    for (int o = 32; o; o >>= 1) v += __shfl_xor(v, o);
    return v;
}

// ---- weight/bias precompute:
// w[0:4]=w2, [4:8]=w3, [8:11]=cb2, [11:14]=cb3, [16:40]=cbM, [64:128]=bavg1
__global__ void k_wvec(const float* __restrict__ fc2, const float* __restrict__ fc3,
                       const float* __restrict__ b1, const float* __restrict__ b2,
                       const float* __restrict__ b3, const float* __restrict__ bM,
                       float* __restrict__ w) {
    __shared__ float w2[4], w3[4];
    int i = threadIdx.x;
    if (i < 4) {
        float a = 0.f, b = 0.f;
        for (int r = 0; r < T_G; r++) { a += fc2[r * T_G + i]; b += fc3[r * T_G + i]; }
        w2[i] = 0.25f * a; w3[i] = 0.25f * b;
        w[i] = w2[i]; w[4 + i] = w3[i];
    }
    __syncthreads();
    if (i < 3) {
        float c = 0.f;
        for (int t = 0; t < T_G; t++) c += w2[t] * b2[t * 3 + i];
        w[8 + i] = c;
    }
    if (i >= 8 && i < 11) {
        int d = i - 8;
        float c = 0.f;
        for (int t = 0; t < T_G; t++) c += w3[t] * b3[t * 3 + d];
        w[11 + d] = c;
    }
    if (i >= 16 && i < 40) {
        int j = i - 16;
        float c = 0.f;
        for (int t = 0; t < T_G; t++) c += w3[t] * bM[t * 24 + j];
        w[16 + j] = c;
    }
    if (i >= 64 && i < 128) {
        int c = i - 64;
        w[i] = 0.25f * (b1[c] + b1[HID_F + c] + b1[2 * HID_F + c] + b1[3 * HID_F + c]);
    }
}

__global__ void k_initrep(float* __restrict__ dst, int n, const float* __restrict__ src, int period) {
    int i = blockIdx.x * 256 + threadIdx.x;
    if (i < n) dst[i] = src[i % period];
}

// ---- layer-1 GEMM: feat1(bf16)[t,n,c], el1/er1
__global__ __launch_bounds__(256) void k_gemm1(
    const float* __restrict__ x, const float* __restrict__ W1,
    const float* __restrict__ al1, const float* __restrict__ ar1,
    __hip_bfloat16* __restrict__ feat1, float* __restrict__ el1, float* __restrict__ er1) {
    __shared__ float Wl[IN_F * HID_F];
    __shared__ float Xl[16 * IN_F];
    int t = blockIdx.y;
    int base = blockIdx.x * 16;
    for (int i = threadIdx.x; i < IN_F * HID_F; i += 256) Wl[i] = W1[t * IN_F * HID_F + i];
    for (int i = threadIdx.x; i < 16 * IN_F; i += 256) Xl[i] = x[base * IN_F + i];
    __syncthreads();
    int c = threadIdx.x & 63;
    int rq = threadIdx.x >> 6;
    float acc[4] = {0.f, 0.f, 0.f, 0.f};
    for (int k = 0; k < IN_F; k++) {
        float w = Wl[k * HID_F + c];
#pragma unroll
        for (int i = 0; i < 4; i++) acc[i] += Xl[(rq * 4 + i) * IN_F + k] * w;
    }
    float alv = al1[t * HID_F + c], arv = ar1[t * HID_F + c];
#pragma unroll
    for (int i = 0; i < 4; i++) {
        int row = base + rq * 4 + i;
        feat1[(t * N_NODES + row) * HID_F + c] = __float2bfloat16(acc[i]);
        float vl = acc[i] * alv, vr = acc[i] * arv;
#pragma unroll
        for (int off = 32; off; off >>= 1) { vl += __shfl_xor(vl, off); vr += __shfl_xor(vr, off); }
        if (c == 0) { el1[t * N_NODES + row] = vl; er1[t * N_NODES + row] = vr; }
    }
}

// ---- CSR build
__global__ void k_count(const int* __restrict__ edges, int* __restrict__ deg) {
    int t = blockIdx.y;
    const int* dst = edges + (t * 2 + 1) * N_EDGES;
    int i = blockIdx.x * blockDim.x + threadIdx.x;
    if (i < N_EDGES) atomicAdd(&deg[t * N_NODES + dst[i]], 1);
}

// 3-phase parallel exclusive scan of deg -> rowptr
__global__ __launch_bounds__(1024) void k_scan1(const int* __restrict__ deg,
                                                int* __restrict__ rowptr, int* __restrict__ bsum) {
    int t = blockIdx.y, b = blockIdx.x;
    int i = b * 1024 + threadIdx.x;
    int lane = threadIdx.x & 63, wid = threadIdx.x >> 6;
    int v = (i < N_NODES) ? deg[t * N_NODES + i] : 0;
    int sc = v;
#pragma unroll
    for (int o = 1; o < 64; o <<= 1) { int u = __shfl_up(sc, o); if (lane >= o) sc += u; }
    __shared__ int ws[16];
    if (lane == 63) ws[wid] = sc;
    __syncthreads();
    if (wid == 0 && lane < 16) {
        int wv = ws[lane];
#pragma unroll
        for (int o = 1; o < 16; o <<= 1) { int u = __shfl_up(wv, o); if (lane >= o) wv += u; }
        ws[lane] = wv;
    }
    __syncthreads();
    int woff = (wid == 0) ? 0 : ws[wid - 1];
    if (i < N_NODES) rowptr[t * N_NODES + i] = woff + sc - v;  // exclusive (block-local)
    if (threadIdx.x == 1023) bsum[t * 64 + b] = woff + sc;     // block total
}

__global__ void k_scan2(int* __restrict__ bsum) {
    int t = threadIdx.x >> 6, lane = threadIdx.x & 63;
    int v = (lane < 49) ? bsum[t * 64 + lane] : 0;
    int sc = v;
#pragma unroll
    for (int o = 1; o < 64; o <<= 1) { int u = __shfl_up(sc, o); if (lane >= o) sc += u; }
    if (lane < 49) bsum[t * 64 + lane] = sc - v;  // exclusive
}

__global__ __launch_bounds__(1024) void k_scan3(int* __restrict__ rowptr, const int* __restrict__ bsum) {
    int t = blockIdx.y, b = blockIdx.x;
    int i = b * 1024 + threadIdx.x;
    if (i < N_NODES) rowptr[t * N_NODES + i] += bsum[t * 64 + b];
}

__global__ void k_scatter(const int* __restrict__ edges, const int* __restrict__ rowptr,
                          int* __restrict__ cursor, int* __restrict__ csr_src) {
    int t = blockIdx.y;
    const int* srcp = edges + (t * 2 + 0) * N_EDGES;
    const int* dstp = edges + (t * 2 + 1) * N_EDGES;
    int i = blockIdx.x * blockDim.x + threadIdx.x;
    if (i < N_EDGES) {
        int d = dstp[i];
        int pos = rowptr[t * N_NODES + d] + atomicAdd(&cursor[t * N_NODES + d], 1);
        csr_src[t * N_EDGES + pos] = srcp[i];
    }
}

// ---- layer-1 aggregation: blockIdx.y = t (L2 locality), wave per node
__global__ __launch_bounds__(256) void k_agg1(
    const __hip_bfloat16* __restrict__ ft_all, const float* __restrict__ el1,
    const float* __restrict__ er1, const int* __restrict__ rowptr,
    const int* __restrict__ deg, const int* __restrict__ csr_src,
    float* __restrict__ h1) {
    int t = blockIdx.y;
    int n = blockIdx.x * 4 + (threadIdx.x >> 6);
    int lane = threadIdx.x & 63;
    int beg = rowptr[t * N_NODES + n], cnt = deg[t * N_NODES + n];
    if (cnt == 0) return;  // h1 pre-biased
    float ern = er1[t * N_NODES + n];
    const int* cs = csr_src + t * N_EDGES;
    const float* el = el1 + t * N_NODES;
    const __hip_bfloat16* ft = ft_all + (long)t * N_NODES * HID_F;
    float acc = 0.f, m_run = -INFINITY, s_run = 0.f;
    for (int c0 = 0; c0 < cnt; c0 += 64) {
        bool valid = (c0 + lane) < cnt;
        int s = valid ? cs[beg + c0 + lane] : 0;
        float e = valid ? lrelu(el[s] + ern) : -INFINITY;
        float cm = wred_max(e);
        float m_new = fmaxf(m_run, cm);
        float scale = (m_run == -INFINITY) ? 0.f : __expf(m_run - m_new);
        float p = valid ? __expf(e - m_new) : 0.f;
        float ps = wred_sum(p);
        s_run = s_run * scale + ps;
        acc *= scale;
        int cn = min(64, cnt - c0);
#pragma unroll 4
        for (int j = 0; j < cn; j++) {
            float pj = __shfl(p, j);
            int sj = __shfl(s, j);
            acc += pj * __bfloat162float(ft[sj * HID_F + lane]);
        }
        m_run = m_new;
    }
    atomicAdd(&h1[n * HID_F + lane], 0.25f * acc / s_run);
}

// ---- layer-2 featurization
__global__ __launch_bounds__(256) void k_feat2(
    const float* __restrict__ h1, const float* __restrict__ W2,
    const float* __restrict__ al2, const float* __restrict__ ar2,
    float* __restrict__ feat2, float* __restrict__ el2, float* __restrict__ er2) {
    __shared__ float Wl[T_G * HID_F * OUT_F];
    __shared__ float Al[T_G * OUT_F], Ar[T_G * OUT_F];
    for (int i = threadIdx.x; i < T_G * HID_F * OUT_F; i += 256) Wl[i] = W2[i];
    if (threadIdx.x < T_G * OUT_F) { Al[threadIdx.x] = al2[threadIdx.x]; Ar[threadIdx.x] = ar2[threadIdx.x]; }
    __syncthreads();
    int n = blockIdx.x * 256 + threadIdx.x;
    if (n >= N_NODES) return;
    float h[HID_F];
    const float4* hp = (const float4*)(h1 + n * HID_F);
#pragma unroll
    for (int i = 0; i < 16; i++) {
        float4 v = hp[i];
        h[4 * i] = v.x; h[4 * i + 1] = v.y; h[4 * i + 2] = v.z; h[4 * i + 3] = v.w;
    }
    for (int t = 0; t < T_G; t++) {
        float f0 = 0.f, f1 = 0.f, f2 = 0.f;
#pragma unroll
        for (int k = 0; k < HID_F; k++) {
            float hv = h[k];
            f0 += hv * Wl[(t * HID_F + k) * 3 + 0];
            f1 += hv * Wl[(t * HID_F + k) * 3 + 1];
            f2 += hv * Wl[(t * HID_F + k) * 3 + 2];
        }
        int ob = (t * N_NODES + n) * 3;
        feat2[ob] = f0; feat2[ob + 1] = f1; feat2[ob + 2] = f2;
        el2[t * N_NODES + n] = f0 * Al[t * 3] + f1 * Al[t * 3 + 1] + f2 * Al[t * 3 + 2];
        er2[t * N_NODES + n] = f0 * Ar[t * 3] + f1 * Ar[t * 3 + 1] + f2 * Ar[t * 3 + 2];
    }
}

// ---- d=3 aggregation: blockIdx.y = t, wave per node
__global__ __launch_bounds__(256) void k_agg3(
    const float* __restrict__ ft_all, const float* __restrict__ el_, const float* __restrict__ er_,
    const int* __restrict__ rowptr, const int* __restrict__ deg, const int* __restrict__ csr_src,
    const float* __restrict__ wv, float* __restrict__ hout) {
    int t = blockIdx.y;
    int n = blockIdx.x * 4 + (threadIdx.x >> 6);
    int lane = threadIdx.x & 63;
    int beg = rowptr[t * N_NODES + n], cnt = deg[t * N_NODES + n];
    if (cnt == 0) return;
    float ern = er_[t * N_NODES + n];
    const int* cs = csr_src + t * N_EDGES;
    const float* el = el_ + t * N_NODES;
    const float* ft = ft_all + (long)t * N_NODES * 3;
    float a0 = 0.f, a1 = 0.f, a2 = 0.f, m_run = -INFINITY, s_run = 0.f;
    for (int c0 = 0; c0 < cnt; c0 += 64) {
        bool valid = (c0 + lane) < cnt;
        int s = valid ? cs[beg + c0 + lane] : 0;
        float e = valid ? lrelu(el[s] + ern) : -INFINITY;
        float cm = wred_max(e);
        float m_new = fmaxf(m_run, cm);
        float scale = (m_run == -INFINITY) ? 0.f : __expf(m_run - m_new);
        float p = valid ? __expf(e - m_new) : 0.f;
        float ps = wred_sum(p);
        s_run = s_run * scale + ps;
        a0 = a0 * scale + p * ft[s * 3 + 0];
        a1 = a1 * scale + p * ft[s * 3 + 1];
        a2 = a2 * scale + p * ft[s * 3 + 2];
        m_run = m_new;
    }
    a0 = wred_sum(a0); a1 = wred_sum(a1); a2 = wred_sum(a2);
    float wt = wv[t] / s_run;
    if (lane < 3) {
        float v = (lane == 0) ? a0 : (lane == 1) ? a1 : a2;
        atomicAdd(&hout[n * 3 + lane], wt * v);
    }
}

// ---- layer-3 featurization (3->3)
__global__ void k_feat3(const float* __restrict__ h2, const float* __restrict__ W3,
                        const float* __restrict__ al3, const float* __restrict__ ar3,
                        float* __restrict__ feat3, float* __restrict__ el3, float* __restrict__ er3) {
    int n = blockIdx.x * 256 + threadIdx.x;
    if (n >= N_NODES) return;
    float h0 = h2[n * 3], h1v = h2[n * 3 + 1], h2v = h2[n * 3 + 2];
    for (int t = 0; t < T_G; t++) {
        float el = 0.f, er = 0.f;
#pragma unroll
        for (int d = 0; d < 3; d++) {
            float f = h0 * W3[(t * 3 + 0) * 3 + d] + h1v * W3[(t * 3 + 1) * 3 + d] + h2v * W3[(t * 3 + 2) * 3 + d];
            feat3[(t * N_NODES + n) * 3 + d] = f;
            el += f * al3[t * 3 + d];
            er += f * ar3[t * 3 + d];
        }
        el3[t * N_NODES + n] = el;
        er3[t * N_NODES + n] = er;
    }
}

// ---- layer-M featurization: packed bf16 row rowM[t][n][32] = {el[0:8], f[0:24]}, er f32
__global__ void k_featM(const float* __restrict__ h3, const float* __restrict__ WM,
                        const float* __restrict__ alM, const float* __restrict__ arM,
                        __hip_bfloat16* __restrict__ rowM, float* __restrict__ erM) {
    int n = blockIdx.x * 256 + threadIdx.x;
    if (n >= N_NODES) return;
    float h0 = h3[n * 3], h1v = h3[n * 3 + 1], h2v = h3[n * 3 + 2];
    for (int t = 0; t < T_G; t++) {
        long rb = ((long)t * N_NODES + n) * 32;
#pragma unroll
        for (int hh = 0; hh < H_M; hh++) {
            float el = 0.f, er = 0.f;
#pragma unroll
            for (int d = 0; d < 3; d++) {
                int j = hh * 3 + d;
                float f = h0 * WM[(t * 3 + 0) * 24 + j] + h1v * WM[(t * 3 + 1) * 24 + j] + h2v * WM[(t * 3 + 2) * 24 + j];
                rowM[rb + 8 + j] = __float2bfloat16(f);
                el += f * alM[(t * H_M + hh) * 3 + d];
                er += f * arM[(t * H_M + hh) * 3 + d];
            }
            rowM[rb + hh] = __float2bfloat16(el);
            erM[(t * N_NODES + n) * 8 + hh] = er;
        }
    }
}

// ---- layer-M softmax stats
__global__ __launch_bounds__(256) void k_wM(
    const __hip_bfloat16* __restrict__ rowM, const float* __restrict__ erM,
    const int* __restrict__ rowptr, const int* __restrict__ deg, const int* __restrict__ csr_src,
    float* __restrict__ mM, float* __restrict__ invM) {
    int t = blockIdx.y;
    int n = blockIdx.x * 4 + (threadIdx.x >> 6);
    int lane = threadIdx.x & 63;
    int h = lane & 7, eo = lane >> 3;
    int beg = rowptr[t * N_NODES + n], cnt = deg[t * N_NODES + n];
    float erh = erM[(t * N_NODES + n) * 8 + h];
    const int* cs = csr_src + t * N_EDGES;
    float m_run = -INFINITY, s_run = 0.f;
    for (int c0 = 0; c0 < cnt; c0 += 8) {
        bool valid = (c0 + eo) < cnt;
        int s = valid ? cs[beg + c0 + eo] : 0;
        float elv = __bfloat162float(rowM[((long)t * N_NODES + s) * 32 + h]);
        float e = valid ? lrelu(elv + erh) : -INFINITY;
        float cm = e;
#pragma unroll
        for (int o = 8; o < 64; o <<= 1) cm = fmaxf(cm, __shfl_xor(cm, o));
        float m_new = fmaxf(m_run, cm);
        float scale = (m_run == -INFINITY) ? 0.f : __expf(m_run - m_new);
        float p = valid ? __expf(e - m_new) : 0.f;
        float ps = p;
#pragma unroll
        for (int o = 8; o < 64; o <<= 1) ps += __shfl_xor(ps, o);
        s_run = s_run * scale + ps;
        m_run = m_new;
    }
    if (eo == 0) {
        int idx = (t * N_NODES + n) * 8 + h;
        mM[idx] = (cnt > 0) ? m_run : 0.f;
        invM[idx] = (cnt > 0) ? 1.f / s_run : 0.f;
    }
}

// ---- layer-M aggregation: blockIdx.y = t, wave per node, 2 edges x 24 outputs
__global__ __launch_bounds__(256) void k_aggM(
    const __hip_bfloat16* __restrict__ rowM, const float* __restrict__ erM,
    const float* __restrict__ mM, const float* __restrict__ invM,
    const int* __restrict__ rowptr, const int* __restrict__ deg, const int* __restrict__ csr_src,
    const float* __restrict__ wv, float* __restrict__ hM) {
    int t = blockIdx.y;
    int n = blockIdx.x * 4 + (threadIdx.x >> 6);
    int lane = threadIdx.x & 63;
    int beg = rowptr[t * N_NODES + n], cnt = deg[t * N_NODES + n];
    if (cnt == 0) return;
    int j = lane & 31; if (j > 23) j = 23;
    int eo = lane >> 5;
    int h = j / 3;
    int nb = (t * N_NODES + n) * 8 + h;
    float erh = erM[nb], mh = mM[nb], invh = invM[nb];
    const int* cs = csr_src + t * N_EDGES;
    float acc = 0.f;
    for (int pos = 0; pos < cnt; pos += 2) {
        bool valid = (pos + eo) < cnt;
        int s = cs[beg + pos + (valid ? eo : 0)];
        long rb = ((long)t * N_NODES + s) * 32;
        float elv = __bfloat162float(rowM[rb + h]);
        float f = __bfloat162float(rowM[rb + 8 + j]);
        float p = valid ? __expf(lrelu(elv + erh) - mh) : 0.f;
        acc += p * f;
    }
    acc += __shfl_xor(acc, 32);
    if (lane < 24) atomicAdd(&hM[n * 24 + lane], wv[t] * invh * acc);
}

// ---- delta norms per head + fused top-16-bit histogram
__global__ void k_norms(const float* __restrict__ hM, float* __restrict__ norms,
                        unsigned int* __restrict__ hist1) {
    int idx = blockIdx.x * 256 + threadIdx.x;
    if (idx >= N_NODES * H_M) return;
    int n = idx >> 3, hh = idx & 7;
    float s = 0.f;
#pragma unroll
    for (int d = 0; d < 3; d++) {
        float cur = hM[n * 24 + hh * 3 + d];
        float prev = (n > 0) ? hM[(n - 1) * 24 + hh * 3 + d] : 0.f;
        float dx = cur - prev;
        s += dx * dx;
    }
    float v = sqrtf(s);
    norms[hh * N_NODES + n] = v;
    unsigned int u = __float_as_uint(v);
    atomicAdd(&hist1[hh * 65536 + (u >> 16)], 1u);
}

// block-level exclusive scan helper (256 threads)
__device__ __forceinline__ unsigned int blk_exscan(unsigned int v) {
    int lane = threadIdx.x & 63, wid = threadIdx.x >> 6;
    unsigned int sc = v;
#pragma unroll
    for (int o = 1; o < 64; o <<= 1) { unsigned int u = __shfl_up(sc, o); if (lane >= o) sc += u; }
    __shared__ unsigned int ws[4];
    if (lane == 63) ws[wid] = sc;
    __syncthreads();
    unsigned int woff = 0;
    for (int w = 0; w < wid; w++) woff += ws[w];
    __syncthreads();
    return woff + sc - v;
}

// ---- find top-16 bin containing rank; one block per (head, rank)
__global__ __launch_bounds__(256) void k_findbin(
    const unsigned int* __restrict__ hist1, int* __restrict__ selbin, int* __restrict__ resrank) {
    int hh = blockIdx.x >> 1, k = blockIdx.x & 1;
    unsigned int rank = N_NODES / 2 - 1 + k;  // 24999 / 25000
    const unsigned int* H = hist1 + hh * 65536;
    int tid = threadIdx.x;
    unsigned int local = 0;
    for (int j = 0; j < 256; j++) local += H[tid * 256 + j];
    unsigned int excl = blk_exscan(local);
    if (rank >= excl && rank < excl + local) {
        unsigned int cum = excl;
        for (int j = 0; j < 256; j++) {
            unsigned int c = H[tid * 256 + j];
            if (cum + c > rank) {
                selbin[hh * 2 + k] = tid * 256 + j;
                resrank[hh * 2 + k] = (int)(rank - cum);
                break;
            }
            cum += c;
        }
    }
}

// ---- low-16-bit histogram restricted to selected top bins
__global__ void k_h2(const float* __restrict__ norms, const int* __restrict__ selbin,
                     unsigned int* __restrict__ hist2) {
    int idx = blockIdx.x * 256 + threadIdx.x;
    if (idx >= N_NODES * H_M) return;
    int hh = idx / N_NODES;
    unsigned int u = __float_as_uint(norms[idx]);
    int top = (int)(u >> 16);
#pragma unroll
    for (int k = 0; k < 2; k++)
        if (top == selbin[hh * 2 + k])
            atomicAdd(&hist2[(hh * 2 + k) * 65536 + (u & 0xFFFFu)], 1u);
}

// ---- find exact order-statistic value; one block per (head, rank)
__global__ __launch_bounds__(256) void k_findval(
    const unsigned int* __restrict__ hist2, const int* __restrict__ selbin,
    const int* __restrict__ resrank, float* __restrict__ medpair) {
    int hh = blockIdx.x >> 1, k = blockIdx.x & 1;
    unsigned int rank = (unsigned int)resrank[hh * 2 + k];
    const unsigned int* H = hist2 + (hh * 2 + k) * 65536;
    int tid = threadIdx.x;
    unsigned int local = 0;
    for (int j = 0; j < 256; j++) local += H[tid * 256 + j];
    unsigned int excl = blk_exscan(local);
    if (rank >= excl && rank < excl + local) {
        unsigned int cum = excl;
        for (int j = 0; j < 256; j++) {
            unsigned int c = H[tid * 256 + j];
            if (cum + c > rank) {
                unsigned int u = ((unsigned int)selbin[hh * 2 + k] << 16) | (unsigned int)(tid * 256 + j);
                medpair[hh * 2 + k] = __uint_as_float(u);
                break;
            }
            cum += c;
        }
    }
}

// ---- final: med computed inline from pair
__global__ void k_final(const float* __restrict__ hM, const float* __restrict__ medpair,
                        const float* __restrict__ noise, float* __restrict__ out) {
    int idx = blockIdx.x * 256 + threadIdx.x;
    if (idx >= N_NODES * 24) return;
    int hh = (idx / 3) & 7;
    float med = 0.5f * (medpair[hh * 2] + medpair[hh * 2 + 1]) + 1e-4f;
    float v = hM[idx] / med;
    if (isnan(v)) v = 0.f;
    else if (isinf(v)) v = v > 0.f ? 100.f : -100.f;
    out[idx] = v + 0.3f * noise[idx];
}

extern "C" void kernel_launch(void* const* d_in, const int* in_sizes, int n_in,
                              void* d_out, int out_size, void* d_ws, size_t ws_size,
                              hipStream_t stream) {
    const float* x     = (const float*)d_in[0];
    const int*   edges = (const int*)d_in[1];
    const float* noise = (const float*)d_in[2];
    const float* W1  = (const float*)d_in[3];
    const float* al1 = (const float*)d_in[4];
    const float* ar1 = (const float*)d_in[5];
    const float* b1  = (const float*)d_in[6];
    const float* W2  = (const float*)d_in[7];
    const float* al2 = (const float*)d_in[8];
    const float* ar2 = (const float*)d_in[9];
    const float* b2  = (const float*)d_in[10];
    const float* W3  = (const float*)d_in[11];
    const float* al3 = (const float*)d_in[12];
    const float* ar3 = (const float*)d_in[13];
    const float* b3  = (const float*)d_in[14];
    const float* WM  = (const float*)d_in[15];
    const float* alM = (const float*)d_in[16];
    const float* arM = (const float*)d_in[17];
    const float* bM  = (const float*)d_in[18];
    const float* fc2 = (const float*)d_in[19];
    const float* fc3 = (const float*)d_in[20];
    float* out = (float*)d_out;

    char* basep = (char*)d_ws;
    size_t off = 0;
    auto alloc = [&](size_t bytes) -> void* {
        void* p = basep + off;
        off += (bytes + 255) & ~(size_t)255;
        return p;
    };
    // Region A: feat1 bf16 (25.6 MB); rowM (12.8 MB) aliases it after k_agg1
    char* regA = (char*)alloc((size_t)T_G * N_NODES * HID_F * 2);
    __hip_bfloat16* feat1 = (__hip_bfloat16*)regA;
    __hip_bfloat16* rowM  = (__hip_bfloat16*)regA;
    float* el1 = (float*)alloc((size_t)T_G * N_NODES * 4);
    float* er1 = (float*)alloc((size_t)T_G * N_NODES * 4);
    float* h1  = (float*)alloc((size_t)N_NODES * HID_F * 4);
    float* feat2 = (float*)alloc((size_t)T_G * N_NODES * 3 * 4);
    float* el2 = (float*)alloc((size_t)T_G * N_NODES * 4);
    float* er2 = (float*)alloc((size_t)T_G * N_NODES * 4);
    float* h2  = (float*)alloc((size_t)N_NODES * 3 * 4);
    float* feat3 = (float*)alloc((size_t)T_G * N_NODES * 3 * 4);
    float* el3 = (float*)alloc((size_t)T_G * N_NODES * 4);
    float* er3 = (float*)alloc((size_t)T_G * N_NODES * 4);
    float* h3  = (float*)alloc((size_t)N_NODES * 3 * 4);
    float* erM  = (float*)alloc((size_t)T_G * N_NODES * 8 * 4);
    float* mM   = (float*)alloc((size_t)T_G * N_NODES * 8 * 4);
    float* invM = (float*)alloc((size_t)T_G * N_NODES * 8 * 4);
    float* hM  = (float*)alloc((size_t)N_NODES * 24 * 4);
    float* norms = (float*)alloc((size_t)H_M * N_NODES * 4);
    float* medpair = (float*)alloc(64);
    float* wbuf = (float*)alloc(512);
    int* deg    = (int*)alloc((size_t)T_G * N_NODES * 4);
    int* cursor = (int*)alloc((size_t)T_G * N_NODES * 4);
    int* rowptr = (int*)alloc((size_t)T_G * N_NODES * 4);
    int* bsum   = (int*)alloc((size_t)T_G * 64 * 4);
    int* csr_src = (int*)alloc((size_t)T_G * N_EDGES * 4);
    unsigned int* hist1 = (unsigned int*)alloc((size_t)H_M * 65536 * 4);      // 2 MB
    unsigned int* hist2 = (unsigned int*)alloc((size_t)H_M * 2 * 65536 * 4);  // 4 MB
    int* selbin  = (int*)alloc(64);
    int* resrank = (int*)alloc(64);

    const int NB = (N_NODES + 255) / 256;   // 196
    const int NW = (N_NODES + 3) / 4;       // 12500
    const int NS = (N_NODES + 1023) / 1024; // 49
    const int NE8 = (N_NODES * H_M + 255) / 256;

    hipMemsetAsync(deg, 0, (size_t)T_G * N_NODES * 4, stream);
    hipMemsetAsync(cursor, 0, (size_t)T_G * N_NODES * 4, stream);
    hipMemsetAsync(hist1, 0, (size_t)H_M * 65536 * 4, stream);
    hipMemsetAsync(hist2, 0, (size_t)H_M * 2 * 65536 * 4, stream);

    k_wvec<<<1, 128, 0, stream>>>(fc2, fc3, b1, b2, b3, bM, wbuf);

    // CSR build
    k_count<<<dim3(N_EDGES / 256, T_G), 256, 0, stream>>>(edges, deg);
    k_scan1<<<dim3(NS, T_G), 1024, 0, stream>>>(deg, rowptr, bsum);
    k_scan2<<<1, 256, 0, stream>>>(bsum);
    k_scan3<<<dim3(NS, T_G), 1024, 0, stream>>>(rowptr, bsum);
    k_scatter<<<dim3(N_EDGES / 256, T_G), 256, 0, stream>>>(edges, rowptr, cursor, csr_src);

    // Layer 1
    k_gemm1<<<dim3(N_NODES / 16, T_G), 256, 0, stream>>>(x, W1, al1, ar1, feat1, el1, er1);
    k_initrep<<<(N_NODES * HID_F + 255) / 256, 256, 0, stream>>>(h1, N_NODES * HID_F, wbuf + 64, HID_F);
    k_agg1<<<dim3(NW, T_G), 256, 0, stream>>>(feat1, el1, er1, rowptr, deg, csr_src, h1);

    // Layer 2
    k_feat2<<<NB, 256, 0, stream>>>(h1, W2, al2, ar2, feat2, el2, er2);
    k_initrep<<<(N_NODES * 3 + 255) / 256, 256, 0, stream>>>(h2, N_NODES * 3, wbuf + 8, 3);
    k_agg3<<<dim3(NW, T_G), 256, 0, stream>>>(feat2, el2, er2, rowptr, deg, csr_src, wbuf + 0, h2);

    // Layer 3
    k_feat3<<<NB, 256, 0, stream>>>(h2, W3, al3, ar3, feat3, el3, er3);
    k_initrep<<<(N_NODES * 3 + 255) / 256, 256, 0, stream>>>(h3, N_NODES * 3, wbuf + 11, 3);
    k_agg3<<<dim3(NW, T_G), 256, 0, stream>>>(feat3, el3, er3, rowptr, deg, csr_src, wbuf + 4, h3);

    // Layer M
    k_featM<<<NB, 256, 0, stream>>>(h3, WM, alM, arM, rowM, erM);
    k_wM<<<dim3(NW, T_G), 256, 0, stream>>>(rowM, erM, rowptr, deg, csr_src, mM, invM);
    k_initrep<<<(N_NODES * 24 + 255) / 256, 256, 0, stream>>>(hM, N_NODES * 24, wbuf + 16, 24);
    k_aggM<<<dim3(NW, T_G), 256, 0, stream>>>(rowM, erM, mM, invM, rowptr, deg, csr_src, wbuf + 4, hM);

    // norm_ (telescoped): parallel exact median via 2-level histogram select
    k_norms<<<NE8, 256, 0, stream>>>(hM, norms, hist1);
    k_findbin<<<16, 256, 0, stream>>>(hist1, selbin, resrank);
    k_h2<<<NE8, 256, 0, stream>>>(norms, selbin, hist2);
    k_findval<<<16, 256, 0, stream>>>(hist2, selbin, resrank, medpair);
    k_final<<<(N_NODES * 24 + 255) / 256, 256, 0, stream>>>(hM, medpair, noise, out);
}